// Round 12
// baseline (283.787 us; speedup 1.0000x reference)
//
#include <hip/hip_runtime.h>

// GCN 2-layer fused:  out = relu( A·(A·x)·(W1@W2) + (A·1)⊗(b1ᵀW2) + b2 )
// A = D^-1/2 (Adj + I) D^-1/2.  Both aggregation passes gather f16 rows;
// each wave processes TWO nodes with interleaved gather chains (latency
// overlap). tof16 rides inside k_rank (atomic-latency shadow); w12/cvec ride
// inside k_fill. Final GEMM: MFMA bf16 split-precision, in-place on d_out.
// All __shfl executed unconditionally (exec-masked ds_bpermute undefined).

#define WS_ALIGN(x) (((x) + 255) & ~(size_t)255)

typedef __attribute__((ext_vector_type(8))) short bf16x8;
typedef __attribute__((ext_vector_type(4))) float f32x4;
typedef _Float16 f16x8 __attribute__((ext_vector_type(8)));
typedef _Float16 f16x4 __attribute__((ext_vector_type(4)));

__device__ inline ushort bf16rn(float f) {
    uint u = __float_as_uint(f);
    u = (u + 0x7FFFu + ((u >> 16) & 1u)) >> 16;
    return (ushort)u;
}
__device__ inline float bf16tof(ushort h) {
    return __uint_as_float(((uint)h) << 16);
}

// blocks [0,rb): degree+rank (atomic-latency bound, ~0.5% VALU);
// blocks [rb,grid): x -> f16 conversion (streams in the latency shadow).
__global__ void k_rank_conv(const int* __restrict__ dst, int* __restrict__ deg,
                            int* __restrict__ rank, int E, int N,
                            const float* __restrict__ x, ushort* __restrict__ xh,
                            int n4, int rb) {
    if ((int)blockIdx.x < rb) {
        int tid = blockIdx.x * blockDim.x + threadIdx.x;
        int stride = rb * blockDim.x;
#pragma unroll
        for (int it = 0; it < 8; ++it) {
            int e = tid + it * stride;
            if (e < E) {
                int d = dst[e];
                if ((unsigned)d < (unsigned)N) rank[e] = atomicAdd(&deg[d], 1);
            }
        }
    } else {
        int tid = (blockIdx.x - rb) * blockDim.x + threadIdx.x;
        int stride = (gridDim.x - rb) * blockDim.x;
        for (int i = tid; i < n4; i += stride) {
            float4 v = ((const float4*)x)[i];
            f16x4 h;
            h[0] = (_Float16)v.x;
            h[1] = (_Float16)v.y;
            h[2] = (_Float16)v.z;
            h[3] = (_Float16)v.w;
            ((uint2*)xh)[i] = __builtin_bit_cast(uint2, h);
        }
    }
}

// Block-local exclusive scan of deg (256/block), emits block sums. Also
// computes dinv = rsqrt(deg+1) (self-loop).
__global__ void k_scan1(const int* __restrict__ deg, int* __restrict__ offs,
                        int* __restrict__ bsums, float* __restrict__ dinv, int N) {
    __shared__ int sh[256];
    int i = blockIdx.x * 256 + threadIdx.x;
    int v = (i < N) ? deg[i] : 0;
    if (i < N) dinv[i] = rsqrtf((float)(v + 1));
    sh[threadIdx.x] = v;
    __syncthreads();
    for (int off = 1; off < 256; off <<= 1) {
        int t = (threadIdx.x >= off) ? sh[threadIdx.x - off] : 0;
        __syncthreads();
        sh[threadIdx.x] += t;
        __syncthreads();
    }
    if (i < N) offs[i] = sh[threadIdx.x] - v;
    if (threadIdx.x == 255) bsums[blockIdx.x] = sh[255];
}

// Exclusive scan of up to 512 block sums in one block.
__global__ void k_scan2(int* __restrict__ bsums, int nb) {
    __shared__ int sh[512];
    int tid = threadIdx.x;
    int v = (tid < nb) ? bsums[tid] : 0;
    sh[tid] = v;
    __syncthreads();
    for (int off = 1; off < 512; off <<= 1) {
        int t = (tid >= off) ? sh[tid - off] : 0;
        __syncthreads();
        sh[tid] += t;
        __syncthreads();
    }
    if (tid < nb) bsums[tid] = sh[tid] - v;
}

__global__ void k_scan3(int* __restrict__ offs, const int* __restrict__ bsums, int N, int E) {
    int i = blockIdx.x * 256 + threadIdx.x;
    if (i < N) offs[i] += bsums[blockIdx.x];
    if (blockIdx.x == 0 && threadIdx.x == 0) offs[N] = E;
}

// blocks [0,fb): atomic-free CSR fill (slot = offs[dst] + rank);
// blocks [fb,fb+64): w12 = W1@W2; block fb+64: cvec = b1^T W2.
__global__ void k_fill_w12(const int* __restrict__ src, const int* __restrict__ dst,
                           const int* __restrict__ rank, const int* __restrict__ offs,
                           int* __restrict__ csr, int E, int N,
                           const float* __restrict__ W1, const float* __restrict__ b1,
                           const float* __restrict__ W2,
                           float* __restrict__ w12, float* __restrict__ cvec, int fb) {
    int bid = blockIdx.x;
    if (bid < fb) {
        int tid = bid * blockDim.x + threadIdx.x;
        int stride = fb * blockDim.x;
#pragma unroll
        for (int it = 0; it < 8; ++it) {
            int e = tid + it * stride;
            if (e < E) {
                int d = dst[e];
                int s = src[e];
                int r = rank[e];
                if ((unsigned)d < (unsigned)N && (unsigned)s < (unsigned)N)
                    csr[offs[d] + r] = s;
            }
        }
    } else if (bid < fb + 64) {
        int idx = (bid - fb) * 256 + threadIdx.x;  // 0..16383
        int i = idx >> 7, j = idx & 127;
        float s = 0.f;
#pragma unroll 8
        for (int k = 0; k < 128; ++k) s = fmaf(W1[i * 128 + k], W2[k * 128 + j], s);
        w12[idx] = s;
    } else {
        int j = threadIdx.x;
        if (j < 128) {
            float s = 0.f;
#pragma unroll 8
            for (int k = 0; k < 128; ++k) s = fmaf(b1[k], W2[k * 128 + j], s);
            cvec[j] = s;
        }
    }
}

// Aggregation over f16 rows, TWO nodes per wave (A = 2w, B = 2w+1): the two
// nodes' dependent chains (csr -> dinv -> bpermute -> row gather -> fma)
// interleave, hiding each other's latency. Quarter-wave (16 lanes) covers a
// 256B f16 row via uint4. Inner math compiles to v_fma_mix_f32.
// WRITE_Q=1: f16 rows out + svec = rowsum(A). WRITE_Q=0: f32 rows to fout.
template <int WRITE_Q>
__launch_bounds__(256)
__global__ void k_aggq(const ushort* __restrict__ xh, const float* __restrict__ dinv,
                       float* __restrict__ fout, ushort* __restrict__ qout,
                       float* __restrict__ svec,
                       const int* __restrict__ offs, const int* __restrict__ csr, int N) {
    int wid = (int)((blockIdx.x * (size_t)blockDim.x + threadIdx.x) >> 6);
    int lane = threadIdx.x & 63;
    int gwA = 2 * wid, gwB = 2 * wid + 1;
    if (gwA >= N) return;
    bool vB = (gwB < N);
    int q = lane >> 4, ql = lane & 15;
    float diA = dinv[gwA];
    float diB = vB ? dinv[gwB] : 0.f;
    const uint4* __restrict__ xh4 = (const uint4*)xh;

    float accA[8], accB[8];
#pragma unroll
    for (int j = 0; j < 8; ++j) { accA[j] = 0.f; accB[j] = 0.f; }
    float ssA = (lane == 0) ? diA : 0.f;
    float ssB = (lane == 0) ? diB : 0.f;

    if (q == 0) {  // self terms
        uint4 va = xh4[((size_t)gwA << 4) + ql];
        f16x8 ha = __builtin_bit_cast(f16x8, va);
#pragma unroll
        for (int j = 0; j < 8; ++j) accA[j] = diA * (float)ha[j];
        if (vB) {
            uint4 vb = xh4[((size_t)gwB << 4) + ql];
            f16x8 hb = __builtin_bit_cast(f16x8, vb);
#pragma unroll
            for (int j = 0; j < 8; ++j) accB[j] = diB * (float)hb[j];
        }
    }

    // offs contiguity: offs[gwB] == offs[gwA+1]
    int s0A = offs[gwA], s1A = offs[gwA + 1];
    int s0B = s1A, s1B = vB ? offs[gwB + 2 - 1 + 0 + 0] : s1A;  // offs[gwB+1]
    if (vB) s1B = offs[gwB + 1];

    int baseA = s0A, baseB = s0B;
    while (baseA < s1A || baseB < s1B) {
        int cA = s1A - baseA; cA = cA < 0 ? 0 : (cA > 64 ? 64 : cA);
        int cB = s1B - baseB; cB = cB < 0 ? 0 : (cB > 64 ? 64 : cB);
        int sidxA = 0, sidxB = 0;
        float dvA = 0.f, dvB = 0.f;   // padded lanes keep 0 -> contribute 0
        if (lane < cA) {
            sidxA = csr[baseA + lane];
            dvA = dinv[sidxA];
        }
        if (lane < cB) {
            sidxB = csr[baseB + lane];
            dvB = dinv[sidxB];
        }
        int itA = (cA + 3) >> 2, itB = (cB + 3) >> 2;
        int iters = itA > itB ? itA : itB;
#pragma unroll 2
        for (int i = 0; i < iters; ++i) {
            int t = 4 * i + q;   // t <= 63 always
            // shfls outside divergent guards (all source lanes active)
            int sA = __shfl(sidxA, t);
            float dA = __shfl(dvA, t);
            int sB = __shfl(sidxB, t);
            float dB = __shfl(dvB, t);
            if (t < cA) {
                uint4 v = xh4[((size_t)sA << 4) + ql];
                f16x8 h = __builtin_bit_cast(f16x8, v);
#pragma unroll
                for (int j = 0; j < 8; ++j) accA[j] = fmaf(dA, (float)h[j], accA[j]);
                if (WRITE_Q && ql == 0) ssA += dA;
            }
            if (t < cB) {
                uint4 v = xh4[((size_t)sB << 4) + ql];
                f16x8 h = __builtin_bit_cast(f16x8, v);
#pragma unroll
                for (int j = 0; j < 8; ++j) accB[j] = fmaf(dB, (float)h[j], accB[j]);
                if (WRITE_Q && ql == 0) ssB += dB;
            }
        }
        baseA += 64;
        baseB += 64;
    }

    // butterfly combine: every lane ends with the full sum of its slice
#pragma unroll
    for (int j = 0; j < 8; ++j) {
        accA[j] += __shfl_xor(accA[j], 16);
        accA[j] += __shfl_xor(accA[j], 32);
        accA[j] *= diA;
        accB[j] += __shfl_xor(accB[j], 16);
        accB[j] += __shfl_xor(accB[j], 32);
        accB[j] *= diB;
    }

    if (WRITE_Q) {
        ssA += __shfl_xor(ssA, 16);
        ssA += __shfl_xor(ssA, 32);
        ssB += __shfl_xor(ssB, 16);
        ssB += __shfl_xor(ssB, 32);
        if (lane == 0) {
            svec[gwA] = diA * ssA;
            if (vB) svec[gwB] = diB * ssB;
        }
        if (q == 0) {
            f16x8 ha, hb;
#pragma unroll
            for (int j = 0; j < 8; ++j) { ha[j] = (_Float16)accA[j]; hb[j] = (_Float16)accB[j]; }
            *(uint4*)(qout + (size_t)gwA * 128 + ql * 8) = __builtin_bit_cast(uint4, ha);
            if (vB) *(uint4*)(qout + (size_t)gwB * 128 + ql * 8) = __builtin_bit_cast(uint4, hb);
        }
    } else {
        if (q == 0) {
            float4 o0, o1;
            o0.x = accA[0]; o0.y = accA[1]; o0.z = accA[2]; o0.w = accA[3];
            o1.x = accA[4]; o1.y = accA[5]; o1.z = accA[6]; o1.w = accA[7];
            *(float4*)(fout + (size_t)gwA * 128 + ql * 8) = o0;
            *(float4*)(fout + (size_t)gwA * 128 + ql * 8 + 4) = o1;
            if (vB) {
                float4 p0, p1;
                p0.x = accB[0]; p0.y = accB[1]; p0.z = accB[2]; p0.w = accB[3];
                p1.x = accB[4]; p1.y = accB[5]; p1.z = accB[6]; p1.w = accB[7];
                *(float4*)(fout + (size_t)gwB * 128 + ql * 8) = p0;
                *(float4*)(fout + (size_t)gwB * 128 + ql * 8 + 4) = p1;
            }
        }
    }
}

// Pack W12 into MFMA B-fragment order, bf16 hi + lo residual.
// Fragment (nt, kb): lane l holds B[kb*32 + (l>>4)*8 + i][nt*16 + (l&15)],
// i = 0..7, stored as 16B at ((nt*4+kb)*64 + l)*16.
__global__ void k_wpack(const float* __restrict__ w12,
                        ushort* __restrict__ wph, ushort* __restrict__ wpl) {
    int idx = blockIdx.x * 256 + threadIdx.x;  // 0..2047
    int lane = idx & 63;
    int kb = (idx >> 6) & 3;
    int nt = idx >> 8;
    int n = nt * 16 + (lane & 15);
    int k0 = kb * 32 + (lane >> 4) * 8;
    ushort h[8], l[8];
#pragma unroll
    for (int i = 0; i < 8; ++i) {
        float f = w12[(k0 + i) * 128 + n];
        h[i] = bf16rn(f);
        l[i] = bf16rn(f - bf16tof(h[i]));
    }
    uint4 oh, ol;
    oh.x = (uint)h[0] | ((uint)h[1] << 16);
    oh.y = (uint)h[2] | ((uint)h[3] << 16);
    oh.z = (uint)h[4] | ((uint)h[5] << 16);
    oh.w = (uint)h[6] | ((uint)h[7] << 16);
    ol.x = (uint)l[0] | ((uint)l[1] << 16);
    ol.y = (uint)l[2] | ((uint)l[3] << 16);
    ol.z = (uint)l[4] | ((uint)l[5] << 16);
    ol.w = (uint)l[6] | ((uint)l[7] << 16);
    ((uint4*)wph)[idx] = oh;
    ((uint4*)wpl)[idx] = ol;
}

// out = relu( X @ W12 + svec ⊗ cvec + b2 ) — MFMA bf16 split-precision
// (X@W = Xhi·Whi + Xlo·Whi + Xhi·Wlo). 256 threads / 4 waves; block covers
// 128 rows; wave owns 32 rows x all 8 col-tiles. W fragments in LDS (64KB).
// In-place safe (X == out): all A loads precede all stores within a block.
__launch_bounds__(256)
__global__ void k_gemm_mfma(const float* __restrict__ X,
                            const ushort* __restrict__ wph, const ushort* __restrict__ wpl,
                            const float* __restrict__ svec, const float* __restrict__ cvec,
                            const float* __restrict__ b2, float* __restrict__ out, int N) {
    __shared__ uint4 wsh[2048];  // 32 KB
    __shared__ uint4 wsl[2048];  // 32 KB
    int tid = threadIdx.x;
    int lane = tid & 63;
    int wv = tid >> 6;
    int row0 = blockIdx.x * 128;

#pragma unroll
    for (int it = 0; it < 8; ++it) {
        wsh[it * 256 + tid] = ((const uint4*)wph)[it * 256 + tid];
        wsl[it * 256 + tid] = ((const uint4*)wpl)[it * 256 + tid];
    }

    // A fragments: strip s (16 rows), k-block kb. lane l: row = base+(l&15),
    // k = kb*32 + (l>>4)*8 + i
    bf16x8 ah[2][4], al[2][4];
#pragma unroll
    for (int s = 0; s < 2; ++s) {
#pragma unroll
        for (int kb = 0; kb < 4; ++kb) {
            int row = row0 + wv * 32 + s * 16 + (lane & 15);
            int kbase = kb * 32 + (lane >> 4) * 8;
            float f[8];
            if (row < N) {
                float4 a = *(const float4*)(X + (size_t)row * 128 + kbase);
                float4 b = *(const float4*)(X + (size_t)row * 128 + kbase + 4);
                f[0] = a.x; f[1] = a.y; f[2] = a.z; f[3] = a.w;
                f[4] = b.x; f[5] = b.y; f[6] = b.z; f[7] = b.w;
            } else {
#pragma unroll
                for (int i = 0; i < 8; ++i) f[i] = 0.f;
            }
            bf16x8 hh, ll;
#pragma unroll
            for (int i = 0; i < 8; ++i) {
                ushort h = bf16rn(f[i]);
                hh[i] = (short)h;
                ll[i] = (short)bf16rn(f[i] - bf16tof(h));
            }
            ah[s][kb] = hh;
            al[s][kb] = ll;
        }
    }
    __syncthreads();

    f32x4 acc[2][8];
#pragma unroll
    for (int s = 0; s < 2; ++s)
#pragma unroll
        for (int nt = 0; nt < 8; ++nt) acc[s][nt] = (f32x4)(0.f);

#pragma unroll
    for (int nt = 0; nt < 8; ++nt) {
#pragma unroll
        for (int kb = 0; kb < 4; ++kb) {
            uint4 rh = wsh[(nt * 4 + kb) * 64 + lane];
            uint4 rl = wsl[(nt * 4 + kb) * 64 + lane];
            bf16x8 bh = __builtin_bit_cast(bf16x8, rh);
            bf16x8 bl = __builtin_bit_cast(bf16x8, rl);
            acc[0][nt] = __builtin_amdgcn_mfma_f32_16x16x32_bf16(ah[0][kb], bh, acc[0][nt], 0, 0, 0);
            acc[0][nt] = __builtin_amdgcn_mfma_f32_16x16x32_bf16(al[0][kb], bh, acc[0][nt], 0, 0, 0);
            acc[0][nt] = __builtin_amdgcn_mfma_f32_16x16x32_bf16(ah[0][kb], bl, acc[0][nt], 0, 0, 0);
            acc[1][nt] = __builtin_amdgcn_mfma_f32_16x16x32_bf16(ah[1][kb], bh, acc[1][nt], 0, 0, 0);
            acc[1][nt] = __builtin_amdgcn_mfma_f32_16x16x32_bf16(al[1][kb], bh, acc[1][nt], 0, 0, 0);
            acc[1][nt] = __builtin_amdgcn_mfma_f32_16x16x32_bf16(ah[1][kb], bl, acc[1][nt], 0, 0, 0);
        }
    }

    float cv[8], bv[8];
#pragma unroll
    for (int nt = 0; nt < 8; ++nt) {
        cv[nt] = cvec[nt * 16 + (lane & 15)];
        bv[nt] = b2[nt * 16 + (lane & 15)];
    }
#pragma unroll
    for (int s = 0; s < 2; ++s) {
#pragma unroll
        for (int r = 0; r < 4; ++r) {
            int row = row0 + wv * 32 + s * 16 + (lane >> 4) * 4 + r;
            if (row < N) {
                float sv = svec[row];
#pragma unroll
                for (int nt = 0; nt < 8; ++nt) {
                    float o = fmaxf(acc[s][nt][r] + sv * cv[nt] + bv[nt], 0.f);
                    out[(size_t)row * 128 + nt * 16 + (lane & 15)] = o;
                }
            }
        }
    }
}

extern "C" void kernel_launch(void* const* d_in, const int* in_sizes, int n_in,
                              void* d_out, int out_size, void* d_ws, size_t ws_size,
                              hipStream_t stream) {
    const float* x  = (const float*)d_in[0];
    const int*   ei = (const int*)d_in[1];
    const float* W1 = (const float*)d_in[2];
    const float* b1 = (const float*)d_in[3];
    const float* W2 = (const float*)d_in[4];
    const float* b2 = (const float*)d_in[5];
    float* out = (float*)d_out;

    int N = in_sizes[0] / 128;
    int E = in_sizes[1] / 2;
    const int* srcE = ei;
    const int* dstE = ei + E;

    char* w = (char*)d_ws;
    size_t off = 0;
    auto alloc = [&](size_t bytes) {
        void* p = w + off;
        off = WS_ALIGN(off + bytes);
        return p;
    };
    ushort* xh    = (ushort*)alloc((size_t)N * 256);
    ushort* t1h   = (ushort*)alloc((size_t)N * 256);   // rank aliases here early
    int*   csr    = (int*)alloc((size_t)E * 4);
    int*   deg    = (int*)alloc((size_t)N * 4);
    int*   offs   = (int*)alloc((size_t)(N + 1) * 4);
    int*   bsums  = (int*)alloc(4096);
    float* dinv   = (float*)alloc((size_t)N * 4);
    float* svec   = (float*)alloc((size_t)N * 4);
    float* w12    = (float*)alloc(128 * 128 * 4);
    ushort* wph   = (ushort*)alloc(128 * 128 * 2);
    ushort* wpl   = (ushort*)alloc(128 * 128 * 2);
    float* cvec   = (float*)alloc(128 * 4);
    (void)ws_size; (void)n_in; (void)out_size;

    int nb = (N + 255) / 256;  // 391 for N=100000, fits k_scan2's 512
    int eb8 = (E + 8 * 256 - 1) / (8 * 256);
    int* rank = (int*)t1h;  // dead before t1h is written (stream-ordered)

    hipMemsetAsync(deg, 0, (size_t)N * 4, stream);
    // rank (atomic wall) with x->f16 conversion riding in its latency shadow
    k_rank_conv<<<eb8 + 1024, 256, 0, stream>>>(dstE, deg, rank, E, N,
                                                x, xh, N * 128 / 4, eb8);
    k_scan1<<<nb, 256, 0, stream>>>(deg, offs, bsums, dinv, N);
    k_scan2<<<1, 512, 0, stream>>>(bsums, nb);
    k_scan3<<<nb, 256, 0, stream>>>(offs, bsums, N, E);
    // CSR fill with w12 / cvec riding along as extra blocks
    k_fill_w12<<<eb8 + 65, 256, 0, stream>>>(srcE, dstE, rank, offs, csr, E, N,
                                             W1, b1, W2, w12, cvec, eb8);
    // pass 1: t1 = A x   (f16 in, f16 out) + svec = rowsum(A)
    k_aggq<1><<<(N + 7) / 8, 256, 0, stream>>>(xh, dinv, nullptr, t1h, svec,
                                               offs, csr, N);
    // pass 2: t2 = A t1  (f16 in, f32 out -> d_out as scratch)
    k_aggq<0><<<(N + 7) / 8, 256, 0, stream>>>(t1h, dinv, out, nullptr, nullptr,
                                               offs, csr, N);
    k_wpack<<<8, 256, 0, stream>>>(w12, wph, wpl);
    // out = relu(t2 @ W12 + svec ⊗ cvec + b2), MFMA, in-place on d_out
    k_gemm_mfma<<<(N + 127) / 128, 256, 0, stream>>>(out, wph, wpl, svec, cvec, b2, out, N);
}

// Round 13
// 281.388 us; speedup vs baseline: 1.0085x; 1.0085x over previous
//
#include <hip/hip_runtime.h>

// GCN 2-layer fused:  out = relu( A·(A·x)·(W1@W2) + (A·1)⊗(b1ᵀW2) + b2 )
// A = D^-1/2 (Adj + I) D^-1/2.
// Aggregation gathers PRE-SCALED f16 rows (xh[s] = dinv[s]*x[s]) -> inner
// loop is pure sum, no per-edge weight gather/bpermute. Two nodes per wave
// (latency overlap). deg counters padded 1-per-64B-line (atomic same-line
// serialization fix). conv/w12/cvec ride in k_fill's latency shadow.
// Final GEMM: MFMA bf16 split-precision, in-place on d_out.
// All __shfl executed unconditionally (exec-masked ds_bpermute undefined).

#define WS_ALIGN(x) (((x) + 255) & ~(size_t)255)
#define DEGPAD 16   // ints per counter line

typedef __attribute__((ext_vector_type(8))) short bf16x8;
typedef __attribute__((ext_vector_type(4))) float f32x4;
typedef _Float16 f16x8 __attribute__((ext_vector_type(8)));
typedef _Float16 f16x4 __attribute__((ext_vector_type(4)));

__device__ inline ushort bf16rn(float f) {
    uint u = __float_as_uint(f);
    u = (u + 0x7FFFu + ((u >> 16) & 1u)) >> 16;
    return (ushort)u;
}
__device__ inline float bf16tof(ushort h) {
    return __uint_as_float(((uint)h) << 16);
}

// degree+rank, counters padded one per 64B line (parallel across L2 slices).
__global__ void k_rank(const int* __restrict__ dst, int* __restrict__ deg16,
                       int* __restrict__ rank, int E, int N) {
    int tid = blockIdx.x * blockDim.x + threadIdx.x;
    int stride = gridDim.x * blockDim.x;
#pragma unroll
    for (int it = 0; it < 8; ++it) {
        int e = tid + it * stride;
        if (e < E) {
            int d = dst[e];
            if ((unsigned)d < (unsigned)N)
                rank[e] = atomicAdd(&deg16[(size_t)d * DEGPAD], 1);
        }
    }
}

// Block-local exclusive scan of deg (256/block), emits block sums. Also
// computes dinv = rsqrt(deg+1) (self-loop).
__global__ void k_scan1(const int* __restrict__ deg16, int* __restrict__ offs,
                        int* __restrict__ bsums, float* __restrict__ dinv, int N) {
    __shared__ int sh[256];
    int i = blockIdx.x * 256 + threadIdx.x;
    int v = (i < N) ? deg16[(size_t)i * DEGPAD] : 0;
    if (i < N) dinv[i] = rsqrtf((float)(v + 1));
    sh[threadIdx.x] = v;
    __syncthreads();
    for (int off = 1; off < 256; off <<= 1) {
        int t = (threadIdx.x >= off) ? sh[threadIdx.x - off] : 0;
        __syncthreads();
        sh[threadIdx.x] += t;
        __syncthreads();
    }
    if (i < N) offs[i] = sh[threadIdx.x] - v;
    if (threadIdx.x == 255) bsums[blockIdx.x] = sh[255];
}

// Exclusive scan of up to 512 block sums in one block.
__global__ void k_scan2(int* __restrict__ bsums, int nb) {
    __shared__ int sh[512];
    int tid = threadIdx.x;
    int v = (tid < nb) ? bsums[tid] : 0;
    sh[tid] = v;
    __syncthreads();
    for (int off = 1; off < 512; off <<= 1) {
        int t = (tid >= off) ? sh[tid - off] : 0;
        __syncthreads();
        sh[tid] += t;
        __syncthreads();
    }
    if (tid < nb) bsums[tid] = sh[tid] - v;
}

__global__ void k_scan3(int* __restrict__ offs, const int* __restrict__ bsums, int N, int E) {
    int i = blockIdx.x * 256 + threadIdx.x;
    if (i < N) offs[i] += bsums[blockIdx.x];
    if (blockIdx.x == 0 && threadIdx.x == 0) offs[N] = E;
}

// blocks [0,fb): atomic-free CSR fill (slot = offs[dst]+rank, latency-bound);
// blocks [fb,fb+cb): x -> f16 PRE-SCALED by dinv (needs dinv: after scan1);
// blocks [fb+cb,fb+cb+64): w12 = W1@W2;  last block: cvec = b1^T W2.
__global__ void k_fill_fused(const int* __restrict__ src, const int* __restrict__ dst,
                             const int* __restrict__ rank, const int* __restrict__ offs,
                             int* __restrict__ csr, int E, int N,
                             const float* __restrict__ x, const float* __restrict__ dinv,
                             ushort* __restrict__ xh,
                             const float* __restrict__ W1, const float* __restrict__ b1,
                             const float* __restrict__ W2,
                             float* __restrict__ w12, float* __restrict__ cvec,
                             int fb, int cb) {
    int bid = blockIdx.x;
    if (bid < fb) {
        int tid = bid * blockDim.x + threadIdx.x;
        int stride = fb * blockDim.x;
#pragma unroll
        for (int it = 0; it < 8; ++it) {
            int e = tid + it * stride;
            if (e < E) {
                int d = dst[e];
                int s = src[e];
                int r = rank[e];
                if ((unsigned)d < (unsigned)N && (unsigned)s < (unsigned)N)
                    csr[offs[d] + r] = s;
            }
        }
    } else if (bid < fb + cb) {
        int tid = (bid - fb) * 256 + threadIdx.x;
        int stride = cb * 256;
        int n4 = N * 32;   // float4's
        for (int i = tid; i < n4; i += stride) {
            float4 v = ((const float4*)x)[i];
            float di = dinv[i >> 5];
            f16x4 h;
            h[0] = (_Float16)(di * v.x);
            h[1] = (_Float16)(di * v.y);
            h[2] = (_Float16)(di * v.z);
            h[3] = (_Float16)(di * v.w);
            ((uint2*)xh)[i] = __builtin_bit_cast(uint2, h);
        }
    } else if (bid < fb + cb + 64) {
        int idx = (bid - fb - cb) * 256 + threadIdx.x;  // 0..16383
        int i = idx >> 7, j = idx & 127;
        float s = 0.f;
#pragma unroll 8
        for (int k = 0; k < 128; ++k) s = fmaf(W1[i * 128 + k], W2[k * 128 + j], s);
        w12[idx] = s;
    } else {
        int j = threadIdx.x;
        if (j < 128) {
            float s = 0.f;
#pragma unroll 8
            for (int k = 0; k < 128; ++k) s = fmaf(b1[k], W2[k * 128 + j], s);
            cvec[j] = s;
        }
    }
}

// Aggregation over PRE-SCALED f16 rows; TWO nodes per wave (A=2w, B=2w+1).
// Inner loop: bpermute sidx + row gather + pure f32 add (no weight).
// WRITE_Q=1: out rows = f16(di^2 * sum) (pre-scaled for next pass) + svec;
//            per-edge dinv loaded per-lane once (svec only), reduced at end.
// WRITE_Q=0: out rows = f32(di * sum) to fout.
template <int WRITE_Q>
__launch_bounds__(256)
__global__ void k_aggq(const ushort* __restrict__ xh, const float* __restrict__ dinv,
                       float* __restrict__ fout, ushort* __restrict__ qout,
                       float* __restrict__ svec,
                       const int* __restrict__ offs, const int* __restrict__ csr, int N) {
    int wid = (int)((blockIdx.x * (size_t)blockDim.x + threadIdx.x) >> 6);
    int lane = threadIdx.x & 63;
    int gwA = 2 * wid, gwB = 2 * wid + 1;
    if (gwA >= N) return;
    bool vB = (gwB < N);
    int q = lane >> 4, ql = lane & 15;
    float diA = dinv[gwA];
    float diB = vB ? dinv[gwB] : 0.f;
    const uint4* __restrict__ xh4 = (const uint4*)xh;

    float accA[8], accB[8];
#pragma unroll
    for (int j = 0; j < 8; ++j) { accA[j] = 0.f; accB[j] = 0.f; }
    float sdA = 0.f, sdB = 0.f;   // per-lane partial of sum dinv[s]

    if (q == 0) {  // self terms: pre-scaled row IS dinv[i]*x[i]
        uint4 va = xh4[((size_t)gwA << 4) + ql];
        f16x8 ha = __builtin_bit_cast(f16x8, va);
#pragma unroll
        for (int j = 0; j < 8; ++j) accA[j] = (float)ha[j];
        if (vB) {
            uint4 vb = xh4[((size_t)gwB << 4) + ql];
            f16x8 hb = __builtin_bit_cast(f16x8, vb);
#pragma unroll
            for (int j = 0; j < 8; ++j) accB[j] = (float)hb[j];
        }
    }

    int s0A = offs[gwA], s1A = offs[gwA + 1];
    int s0B = s1A;
    int s1B = vB ? offs[gwB + 1] : s1A;

    int baseA = s0A, baseB = s0B;
    while (baseA < s1A || baseB < s1B) {
        int cA = s1A - baseA; cA = cA < 0 ? 0 : (cA > 64 ? 64 : cA);
        int cB = s1B - baseB; cB = cB < 0 ? 0 : (cB > 64 ? 64 : cB);
        int sidxA = 0, sidxB = 0;
        if (lane < cA) sidxA = csr[baseA + lane];
        if (lane < cB) sidxB = csr[baseB + lane];
        if (WRITE_Q) {   // svec needs sum dinv[s]; per-lane, no bpermute
            if (lane < cA) sdA += dinv[sidxA];
            if (lane < cB) sdB += dinv[sidxB];
        }
        int itA = (cA + 3) >> 2, itB = (cB + 3) >> 2;
        int iters = itA > itB ? itA : itB;
#pragma unroll 2
        for (int i = 0; i < iters; ++i) {
            int t = 4 * i + q;   // t <= 63 always
            // shfls outside divergent guards (all source lanes active)
            int sA = __shfl(sidxA, t);
            int sB = __shfl(sidxB, t);
            if (t < cA) {
                uint4 v = xh4[((size_t)sA << 4) + ql];
                f16x8 h = __builtin_bit_cast(f16x8, v);
#pragma unroll
                for (int j = 0; j < 8; ++j) accA[j] += (float)h[j];
            }
            if (t < cB) {
                uint4 v = xh4[((size_t)sB << 4) + ql];
                f16x8 h = __builtin_bit_cast(f16x8, v);
#pragma unroll
                for (int j = 0; j < 8; ++j) accB[j] += (float)h[j];
            }
        }
        baseA += 64;
        baseB += 64;
    }

    // butterfly combine: every lane ends with the full sum of its slice
#pragma unroll
    for (int j = 0; j < 8; ++j) {
        accA[j] += __shfl_xor(accA[j], 16);
        accA[j] += __shfl_xor(accA[j], 32);
        accB[j] += __shfl_xor(accB[j], 16);
        accB[j] += __shfl_xor(accB[j], 32);
    }

    if (WRITE_Q) {
        // full 64-lane reduce of per-lane dinv partials
#pragma unroll
        for (int d = 1; d < 64; d <<= 1) {
            sdA += __shfl_xor(sdA, d);
            sdB += __shfl_xor(sdB, d);
        }
        if (lane == 0) {
            svec[gwA] = diA * (diA + sdA);
            if (vB) svec[gwB] = diB * (diB + sdB);
        }
        if (q == 0) {  // store pre-scaled for pass 2: dinv*t1 = di^2 * sum
            float fA = diA * diA, fB = diB * diB;
            f16x8 ha, hb;
#pragma unroll
            for (int j = 0; j < 8; ++j) {
                ha[j] = (_Float16)(fA * accA[j]);
                hb[j] = (_Float16)(fB * accB[j]);
            }
            *(uint4*)(qout + (size_t)gwA * 128 + ql * 8) = __builtin_bit_cast(uint4, ha);
            if (vB) *(uint4*)(qout + (size_t)gwB * 128 + ql * 8) = __builtin_bit_cast(uint4, hb);
        }
    } else {
        if (q == 0) {  // t2 = di * sum, f32
            float4 o0, o1, p0, p1;
            o0.x = diA * accA[0]; o0.y = diA * accA[1]; o0.z = diA * accA[2]; o0.w = diA * accA[3];
            o1.x = diA * accA[4]; o1.y = diA * accA[5]; o1.z = diA * accA[6]; o1.w = diA * accA[7];
            *(float4*)(fout + (size_t)gwA * 128 + ql * 8) = o0;
            *(float4*)(fout + (size_t)gwA * 128 + ql * 8 + 4) = o1;
            if (vB) {
                p0.x = diB * accB[0]; p0.y = diB * accB[1]; p0.z = diB * accB[2]; p0.w = diB * accB[3];
                p1.x = diB * accB[4]; p1.y = diB * accB[5]; p1.z = diB * accB[6]; p1.w = diB * accB[7];
                *(float4*)(fout + (size_t)gwB * 128 + ql * 8) = p0;
                *(float4*)(fout + (size_t)gwB * 128 + ql * 8 + 4) = p1;
            }
        }
    }
}

// Pack W12 into MFMA B-fragment order, bf16 hi + lo residual.
// Fragment (nt, kb): lane l holds B[kb*32 + (l>>4)*8 + i][nt*16 + (l&15)],
// i = 0..7, stored as 16B at ((nt*4+kb)*64 + l)*16.
__global__ void k_wpack(const float* __restrict__ w12,
                        ushort* __restrict__ wph, ushort* __restrict__ wpl) {
    int idx = blockIdx.x * 256 + threadIdx.x;  // 0..2047
    int lane = idx & 63;
    int kb = (idx >> 6) & 3;
    int nt = idx >> 8;
    int n = nt * 16 + (lane & 15);
    int k0 = kb * 32 + (lane >> 4) * 8;
    ushort h[8], l[8];
#pragma unroll
    for (int i = 0; i < 8; ++i) {
        float f = w12[(k0 + i) * 128 + n];
        h[i] = bf16rn(f);
        l[i] = bf16rn(f - bf16tof(h[i]));
    }
    uint4 oh, ol;
    oh.x = (uint)h[0] | ((uint)h[1] << 16);
    oh.y = (uint)h[2] | ((uint)h[3] << 16);
    oh.z = (uint)h[4] | ((uint)h[5] << 16);
    oh.w = (uint)h[6] | ((uint)h[7] << 16);
    ol.x = (uint)l[0] | ((uint)l[1] << 16);
    ol.y = (uint)l[2] | ((uint)l[3] << 16);
    ol.z = (uint)l[4] | ((uint)l[5] << 16);
    ol.w = (uint)l[6] | ((uint)l[7] << 16);
    ((uint4*)wph)[idx] = oh;
    ((uint4*)wpl)[idx] = ol;
}

// out = relu( X @ W12 + svec ⊗ cvec + b2 ) — MFMA bf16 split-precision
// (X@W = Xhi·Whi + Xlo·Whi + Xhi·Wlo). 256 threads / 4 waves; block covers
// 128 rows; wave owns 32 rows x all 8 col-tiles. W fragments in LDS (64KB).
// In-place safe (X == out): all A loads precede all stores within a block.
__launch_bounds__(256)
__global__ void k_gemm_mfma(const float* __restrict__ X,
                            const ushort* __restrict__ wph, const ushort* __restrict__ wpl,
                            const float* __restrict__ svec, const float* __restrict__ cvec,
                            const float* __restrict__ b2, float* __restrict__ out, int N) {
    __shared__ uint4 wsh[2048];  // 32 KB
    __shared__ uint4 wsl[2048];  // 32 KB
    int tid = threadIdx.x;
    int lane = tid & 63;
    int wv = tid >> 6;
    int row0 = blockIdx.x * 128;

#pragma unroll
    for (int it = 0; it < 8; ++it) {
        wsh[it * 256 + tid] = ((const uint4*)wph)[it * 256 + tid];
        wsl[it * 256 + tid] = ((const uint4*)wpl)[it * 256 + tid];
    }

    bf16x8 ah[2][4], al[2][4];
#pragma unroll
    for (int s = 0; s < 2; ++s) {
#pragma unroll
        for (int kb = 0; kb < 4; ++kb) {
            int row = row0 + wv * 32 + s * 16 + (lane & 15);
            int kbase = kb * 32 + (lane >> 4) * 8;
            float f[8];
            if (row < N) {
                float4 a = *(const float4*)(X + (size_t)row * 128 + kbase);
                float4 b = *(const float4*)(X + (size_t)row * 128 + kbase + 4);
                f[0] = a.x; f[1] = a.y; f[2] = a.z; f[3] = a.w;
                f[4] = b.x; f[5] = b.y; f[6] = b.z; f[7] = b.w;
            } else {
#pragma unroll
                for (int i = 0; i < 8; ++i) f[i] = 0.f;
            }
            bf16x8 hh, ll;
#pragma unroll
            for (int i = 0; i < 8; ++i) {
                ushort h = bf16rn(f[i]);
                hh[i] = (short)h;
                ll[i] = (short)bf16rn(f[i] - bf16tof(h));
            }
            ah[s][kb] = hh;
            al[s][kb] = ll;
        }
    }
    __syncthreads();

    f32x4 acc[2][8];
#pragma unroll
    for (int s = 0; s < 2; ++s)
#pragma unroll
        for (int nt = 0; nt < 8; ++nt) acc[s][nt] = (f32x4)(0.f);

#pragma unroll
    for (int nt = 0; nt < 8; ++nt) {
#pragma unroll
        for (int kb = 0; kb < 4; ++kb) {
            uint4 rh = wsh[(nt * 4 + kb) * 64 + lane];
            uint4 rl = wsl[(nt * 4 + kb) * 64 + lane];
            bf16x8 bh = __builtin_bit_cast(bf16x8, rh);
            bf16x8 bl = __builtin_bit_cast(bf16x8, rl);
            acc[0][nt] = __builtin_amdgcn_mfma_f32_16x16x32_bf16(ah[0][kb], bh, acc[0][nt], 0, 0, 0);
            acc[0][nt] = __builtin_amdgcn_mfma_f32_16x16x32_bf16(al[0][kb], bh, acc[0][nt], 0, 0, 0);
            acc[0][nt] = __builtin_amdgcn_mfma_f32_16x16x32_bf16(ah[0][kb], bl, acc[0][nt], 0, 0, 0);
            acc[1][nt] = __builtin_amdgcn_mfma_f32_16x16x32_bf16(ah[1][kb], bh, acc[1][nt], 0, 0, 0);
            acc[1][nt] = __builtin_amdgcn_mfma_f32_16x16x32_bf16(al[1][kb], bh, acc[1][nt], 0, 0, 0);
            acc[1][nt] = __builtin_amdgcn_mfma_f32_16x16x32_bf16(ah[1][kb], bl, acc[1][nt], 0, 0, 0);
        }
    }

    float cv[8], bv[8];
#pragma unroll
    for (int nt = 0; nt < 8; ++nt) {
        cv[nt] = cvec[nt * 16 + (lane & 15)];
        bv[nt] = b2[nt * 16 + (lane & 15)];
    }
#pragma unroll
    for (int s = 0; s < 2; ++s) {
#pragma unroll
        for (int r = 0; r < 4; ++r) {
            int row = row0 + wv * 32 + s * 16 + (lane >> 4) * 4 + r;
            if (row < N) {
                float sv = svec[row];
#pragma unroll
                for (int nt = 0; nt < 8; ++nt) {
                    float o = fmaxf(acc[s][nt][r] + sv * cv[nt] + bv[nt], 0.f);
                    out[(size_t)row * 128 + nt * 16 + (lane & 15)] = o;
                }
            }
        }
    }
}

extern "C" void kernel_launch(void* const* d_in, const int* in_sizes, int n_in,
                              void* d_out, int out_size, void* d_ws, size_t ws_size,
                              hipStream_t stream) {
    const float* x  = (const float*)d_in[0];
    const int*   ei = (const int*)d_in[1];
    const float* W1 = (const float*)d_in[2];
    const float* b1 = (const float*)d_in[3];
    const float* W2 = (const float*)d_in[4];
    const float* b2 = (const float*)d_in[5];
    float* out = (float*)d_out;

    int N = in_sizes[0] / 128;
    int E = in_sizes[1] / 2;
    const int* srcE = ei;
    const int* dstE = ei + E;

    char* w = (char*)d_ws;
    size_t off = 0;
    auto alloc = [&](size_t bytes) {
        void* p = w + off;
        off = WS_ALIGN(off + bytes);
        return p;
    };
    ushort* xh    = (ushort*)alloc((size_t)N * 256);
    ushort* t1h   = (ushort*)alloc((size_t)N * 256);   // rank aliases here early
    int*   csr    = (int*)alloc((size_t)E * 4);
    int*   deg16  = (int*)alloc((size_t)N * DEGPAD * 4);   // 1 counter / 64B line
    int*   offs   = (int*)alloc((size_t)(N + 1) * 4);
    int*   bsums  = (int*)alloc(4096);
    float* dinv   = (float*)alloc((size_t)N * 4);
    float* svec   = (float*)alloc((size_t)N * 4);
    float* w12    = (float*)alloc(128 * 128 * 4);
    ushort* wph   = (ushort*)alloc(128 * 128 * 2);
    ushort* wpl   = (ushort*)alloc(128 * 128 * 2);
    float* cvec   = (float*)alloc(128 * 4);
    (void)ws_size; (void)n_in; (void)out_size;

    int nb = (N + 255) / 256;  // 391 for N=100000, fits k_scan2's 512
    int eb8 = (E + 8 * 256 - 1) / (8 * 256);
    int cb = 512;              // conversion blocks riding in k_fill
    int* rank = (int*)t1h;     // dead before t1h is written (stream-ordered)

    hipMemsetAsync(deg16, 0, (size_t)N * DEGPAD * 4, stream);
    k_rank<<<eb8, 256, 0, stream>>>(dstE, deg16, rank, E, N);
    k_scan1<<<nb, 256, 0, stream>>>(deg16, offs, bsums, dinv, N);
    k_scan2<<<1, 512, 0, stream>>>(bsums, nb);
    k_scan3<<<nb, 256, 0, stream>>>(offs, bsums, N, E);
    // CSR fill with pre-scaled x->f16 conversion + w12 + cvec riding along
    k_fill_fused<<<eb8 + cb + 65, 256, 0, stream>>>(srcE, dstE, rank, offs, csr, E, N,
                                                    x, dinv, xh, W1, b1, W2,
                                                    w12, cvec, eb8, cb);
    // pass 1: t1h = f16(dinv^2 * sum(xh)) + svec
    k_aggq<1><<<(N + 7) / 8, 256, 0, stream>>>(xh, dinv, nullptr, t1h, svec,
                                               offs, csr, N);
    // pass 2: t2 = f32(dinv * sum(t1h)) -> d_out as scratch
    k_aggq<0><<<(N + 7) / 8, 256, 0, stream>>>(t1h, dinv, out, nullptr, nullptr,
                                               offs, csr, N);
    k_wpack<<<8, 256, 0, stream>>>(w12, wph, wpl);
    // out = relu(t2 @ W12 + svec ⊗ cvec + b2), MFMA, in-place on d_out
    k_gemm_mfma<<<(N + 127) / 128, 256, 0, stream>>>(out, wph, wpl, svec, cvec, b2, out, N);
}

// Round 14
// 229.818 us; speedup vs baseline: 1.2348x; 1.2244x over previous
//
#include <hip/hip_runtime.h>

// GCN 2-layer fused:  out = relu( A·(A·x)·(W1@W2) + (A·1)⊗(b1ᵀW2) + b2 )
// A = D^-1/2 (Adj + I) D^-1/2.
// CSR built ATOMIC-FREE via 2-level binning: per-block LDS histogram of
// bin = dst>>9 -> scanned (bin,block) windows -> partition (packed
// (dlocal<<23)|src) -> per-bin LDS count/scan/fill. Aggregation gathers
// PRE-SCALED f16 rows, two nodes per wave. Final GEMM: MFMA bf16
// split-precision, in-place on d_out.
// All __shfl executed unconditionally (exec-masked ds_bpermute undefined).

#define WS_ALIGN(x) (((x) + 255) & ~(size_t)255)
#define BINSH 9                 // bin = dst >> 9 (512 dsts per bin)
#define EPB 4096                // edges per block in hist/part

typedef __attribute__((ext_vector_type(8))) short bf16x8;
typedef __attribute__((ext_vector_type(4))) float f32x4;
typedef _Float16 f16x8 __attribute__((ext_vector_type(8)));
typedef _Float16 f16x4 __attribute__((ext_vector_type(4)));

__device__ inline ushort bf16rn(float f) {
    uint u = __float_as_uint(f);
    u = (u + 0x7FFFu + ((u >> 16) & 1u)) >> 16;
    return (ushort)u;
}
__device__ inline float bf16tof(ushort h) {
    return __uint_as_float(((uint)h) << 16);
}

// Per-block histogram of dst bins. hist[bin * nblocksB + blk].
__global__ void k_hist(const int* __restrict__ src, const int* __restrict__ dst,
                       int* __restrict__ hist, int E, int N, int nbins, int nblocksB) {
    __shared__ int h[256];
    int tid = threadIdx.x;
    h[tid] = 0;
    __syncthreads();
    int e0 = blockIdx.x * EPB;
#pragma unroll
    for (int i = 0; i < EPB / 256; ++i) {
        int e = e0 + i * 256 + tid;
        if (e < E) {
            int d = dst[e];
            int s = src[e];
            if ((unsigned)d < (unsigned)N && (unsigned)s < (unsigned)N)
                atomicAdd(&h[d >> BINSH], 1);
        }
    }
    __syncthreads();
    if (tid < nbins) hist[tid * nblocksB + blockIdx.x] = h[tid];
}

// Generic exclusive scan over int array (3-kernel pattern, L <= 512*256).
__global__ void k_scanA(const int* __restrict__ in, int* __restrict__ outv,
                        int* __restrict__ bsums, int L) {
    __shared__ int sh[256];
    int i = blockIdx.x * 256 + threadIdx.x;
    int v = (i < L) ? in[i] : 0;
    sh[threadIdx.x] = v;
    __syncthreads();
    for (int off = 1; off < 256; off <<= 1) {
        int t = (threadIdx.x >= off) ? sh[threadIdx.x - off] : 0;
        __syncthreads();
        sh[threadIdx.x] += t;
        __syncthreads();
    }
    if (i < L) outv[i] = sh[threadIdx.x] - v;
    if (threadIdx.x == 255) bsums[blockIdx.x] = sh[255];
}

__global__ void k_scan2(int* __restrict__ bsums, int nb) {
    __shared__ int sh[512];
    int tid = threadIdx.x;
    int v = (tid < nb) ? bsums[tid] : 0;
    sh[tid] = v;
    __syncthreads();
    for (int off = 1; off < 512; off <<= 1) {
        int t = (tid >= off) ? sh[tid - off] : 0;
        __syncthreads();
        sh[tid] += t;
        __syncthreads();
    }
    if (tid < nb) bsums[tid] = sh[tid] - v;
}

__global__ void k_scanB(int* __restrict__ outv, const int* __restrict__ bsums, int L) {
    int i = blockIdx.x * 256 + threadIdx.x;
    if (i < L) outv[i] += bsums[blockIdx.x];
}

// Partition edges into bins. Each (bin,block) window is disjoint -> LDS
// cursor only, global writes are fire-and-forget. payload = (dlocal<<23)|src.
__global__ void k_part(const int* __restrict__ src, const int* __restrict__ dst,
                       const int* __restrict__ hists, uint* __restrict__ part,
                       int E, int N, int nbins, int nblocksB) {
    __shared__ int cur[256];
    int tid = threadIdx.x;
    if (tid < nbins) cur[tid] = hists[tid * nblocksB + blockIdx.x];
    __syncthreads();
    int e0 = blockIdx.x * EPB;
#pragma unroll
    for (int i = 0; i < EPB / 256; ++i) {
        int e = e0 + i * 256 + tid;
        if (e < E) {
            int d = dst[e];
            int s = src[e];
            if ((unsigned)d < (unsigned)N && (unsigned)s < (unsigned)N) {
                int pos = atomicAdd(&cur[d >> BINSH], 1);
                part[pos] = (uint)s | ((uint)(d & 511) << 23);
            }
        }
    }
}

// One block per bin: count its 512 dsts (LDS), scan, emit offs/dinv, then
// fill csr via LDS-atomic rank. csr region for bin b == its partition window.
__global__ void k_bin(const uint* __restrict__ part, const int* __restrict__ hists,
                      const int* __restrict__ hist, int nbins, int nblocksB, int N,
                      int* __restrict__ csr, int* __restrict__ offs,
                      float* __restrict__ dinv) {
    __shared__ int cnt[512];
    __shared__ int loff[512];
    __shared__ int ps[256];
    int b = blockIdx.x;
    int tid = threadIdx.x;
    int start = hists[b * nblocksB];
    int last = nbins * nblocksB - 1;
    int end = (b + 1 < nbins) ? hists[(b + 1) * nblocksB] : (hists[last] + hist[last]);

    cnt[tid] = 0;
    cnt[tid + 256] = 0;
    __syncthreads();
    for (int i = start + tid; i < end; i += 256)
        atomicAdd(&cnt[part[i] >> 23], 1);
    __syncthreads();

    // exclusive scan of cnt[512]: pair-sums then 256-wide Hillis-Steele
    int a0 = cnt[2 * tid], a1 = cnt[2 * tid + 1];
    ps[tid] = a0 + a1;
    __syncthreads();
    for (int off = 1; off < 256; off <<= 1) {
        int t = (tid >= off) ? ps[tid - off] : 0;
        __syncthreads();
        ps[tid] += t;
        __syncthreads();
    }
    int excl = ps[tid] - (a0 + a1);
    loff[2 * tid] = excl;
    loff[2 * tid + 1] = excl + a0;
    __syncthreads();

    // emit offs and dinv for this bin's dst range
    int d0 = b << BINSH;
#pragma unroll
    for (int h = 0; h < 2; ++h) {
        int k = tid + h * 256;
        int d = d0 + k;
        if (d < N) {
            offs[d] = start + loff[k];
            dinv[d] = rsqrtf((float)(cnt[k] + 1));
        }
    }
    if (b == nbins - 1 && tid == 0) offs[N] = end;
    __syncthreads();

    // fill csr: rank via LDS atomic on loff (now cursors)
    for (int i = start + tid; i < end; i += 256) {
        uint p = part[i];
        int pos = atomicAdd(&loff[p >> 23], 1);
        csr[start + pos] = (int)(p & 0x7FFFFFu);
    }
}

// blocks [0,cb): x -> f16 PRE-SCALED by dinv; [cb,cb+64): w12 = W1@W2;
// last block: cvec = b1^T W2.
__global__ void k_conv_w12(const float* __restrict__ x, const float* __restrict__ dinv,
                           ushort* __restrict__ xh, int N,
                           const float* __restrict__ W1, const float* __restrict__ b1,
                           const float* __restrict__ W2,
                           float* __restrict__ w12, float* __restrict__ cvec, int cb) {
    int bid = blockIdx.x;
    if (bid < cb) {
        int tid = bid * 256 + threadIdx.x;
        int stride = cb * 256;
        int n4 = N * 32;   // float4's
        for (int i = tid; i < n4; i += stride) {
            float4 v = ((const float4*)x)[i];
            float di = dinv[i >> 5];
            f16x4 h;
            h[0] = (_Float16)(di * v.x);
            h[1] = (_Float16)(di * v.y);
            h[2] = (_Float16)(di * v.z);
            h[3] = (_Float16)(di * v.w);
            ((uint2*)xh)[i] = __builtin_bit_cast(uint2, h);
        }
    } else if (bid < cb + 64) {
        int idx = (bid - cb) * 256 + threadIdx.x;  // 0..16383
        int i = idx >> 7, j = idx & 127;
        float s = 0.f;
#pragma unroll 8
        for (int k = 0; k < 128; ++k) s = fmaf(W1[i * 128 + k], W2[k * 128 + j], s);
        w12[idx] = s;
    } else {
        int j = threadIdx.x;
        if (j < 128) {
            float s = 0.f;
#pragma unroll 8
            for (int k = 0; k < 128; ++k) s = fmaf(b1[k], W2[k * 128 + j], s);
            cvec[j] = s;
        }
    }
}

// Aggregation over PRE-SCALED f16 rows; TWO nodes per wave (A=2w, B=2w+1).
// WRITE_Q=1: out rows = f16(di^2 * sum) + svec. WRITE_Q=0: f32(di*sum).
template <int WRITE_Q>
__launch_bounds__(256)
__global__ void k_aggq(const ushort* __restrict__ xh, const float* __restrict__ dinv,
                       float* __restrict__ fout, ushort* __restrict__ qout,
                       float* __restrict__ svec,
                       const int* __restrict__ offs, const int* __restrict__ csr, int N) {
    int wid = (int)((blockIdx.x * (size_t)blockDim.x + threadIdx.x) >> 6);
    int lane = threadIdx.x & 63;
    int gwA = 2 * wid, gwB = 2 * wid + 1;
    if (gwA >= N) return;
    bool vB = (gwB < N);
    int q = lane >> 4, ql = lane & 15;
    float diA = dinv[gwA];
    float diB = vB ? dinv[gwB] : 0.f;
    const uint4* __restrict__ xh4 = (const uint4*)xh;

    float accA[8], accB[8];
#pragma unroll
    for (int j = 0; j < 8; ++j) { accA[j] = 0.f; accB[j] = 0.f; }
    float sdA = 0.f, sdB = 0.f;

    if (q == 0) {  // self terms: pre-scaled row IS dinv[i]*x[i]
        uint4 va = xh4[((size_t)gwA << 4) + ql];
        f16x8 ha = __builtin_bit_cast(f16x8, va);
#pragma unroll
        for (int j = 0; j < 8; ++j) accA[j] = (float)ha[j];
        if (vB) {
            uint4 vb = xh4[((size_t)gwB << 4) + ql];
            f16x8 hb = __builtin_bit_cast(f16x8, vb);
#pragma unroll
            for (int j = 0; j < 8; ++j) accB[j] = (float)hb[j];
        }
    }

    int s0A = offs[gwA], s1A = offs[gwA + 1];
    int s0B = s1A;
    int s1B = vB ? offs[gwB + 1] : s1A;

    int baseA = s0A, baseB = s0B;
    while (baseA < s1A || baseB < s1B) {
        int cA = s1A - baseA; cA = cA < 0 ? 0 : (cA > 64 ? 64 : cA);
        int cB = s1B - baseB; cB = cB < 0 ? 0 : (cB > 64 ? 64 : cB);
        int sidxA = 0, sidxB = 0;
        if (lane < cA) sidxA = csr[baseA + lane];
        if (lane < cB) sidxB = csr[baseB + lane];
        if (WRITE_Q) {
            if (lane < cA) sdA += dinv[sidxA];
            if (lane < cB) sdB += dinv[sidxB];
        }
        int itA = (cA + 3) >> 2, itB = (cB + 3) >> 2;
        int iters = itA > itB ? itA : itB;
#pragma unroll 2
        for (int i = 0; i < iters; ++i) {
            int t = 4 * i + q;   // t <= 63 always
            int sA = __shfl(sidxA, t);
            int sB = __shfl(sidxB, t);
            if (t < cA) {
                uint4 v = xh4[((size_t)sA << 4) + ql];
                f16x8 h = __builtin_bit_cast(f16x8, v);
#pragma unroll
                for (int j = 0; j < 8; ++j) accA[j] += (float)h[j];
            }
            if (t < cB) {
                uint4 v = xh4[((size_t)sB << 4) + ql];
                f16x8 h = __builtin_bit_cast(f16x8, v);
#pragma unroll
                for (int j = 0; j < 8; ++j) accB[j] += (float)h[j];
            }
        }
        baseA += 64;
        baseB += 64;
    }

#pragma unroll
    for (int j = 0; j < 8; ++j) {
        accA[j] += __shfl_xor(accA[j], 16);
        accA[j] += __shfl_xor(accA[j], 32);
        accB[j] += __shfl_xor(accB[j], 16);
        accB[j] += __shfl_xor(accB[j], 32);
    }

    if (WRITE_Q) {
#pragma unroll
        for (int d = 1; d < 64; d <<= 1) {
            sdA += __shfl_xor(sdA, d);
            sdB += __shfl_xor(sdB, d);
        }
        if (lane == 0) {
            svec[gwA] = diA * (diA + sdA);
            if (vB) svec[gwB] = diB * (diB + sdB);
        }
        if (q == 0) {
            float fA = diA * diA, fB = diB * diB;
            f16x8 ha, hb;
#pragma unroll
            for (int j = 0; j < 8; ++j) {
                ha[j] = (_Float16)(fA * accA[j]);
                hb[j] = (_Float16)(fB * accB[j]);
            }
            *(uint4*)(qout + (size_t)gwA * 128 + ql * 8) = __builtin_bit_cast(uint4, ha);
            if (vB) *(uint4*)(qout + (size_t)gwB * 128 + ql * 8) = __builtin_bit_cast(uint4, hb);
        }
    } else {
        if (q == 0) {
            float4 o0, o1, p0, p1;
            o0.x = diA * accA[0]; o0.y = diA * accA[1]; o0.z = diA * accA[2]; o0.w = diA * accA[3];
            o1.x = diA * accA[4]; o1.y = diA * accA[5]; o1.z = diA * accA[6]; o1.w = diA * accA[7];
            *(float4*)(fout + (size_t)gwA * 128 + ql * 8) = o0;
            *(float4*)(fout + (size_t)gwA * 128 + ql * 8 + 4) = o1;
            if (vB) {
                p0.x = diB * accB[0]; p0.y = diB * accB[1]; p0.z = diB * accB[2]; p0.w = diB * accB[3];
                p1.x = diB * accB[4]; p1.y = diB * accB[5]; p1.z = diB * accB[6]; p1.w = diB * accB[7];
                *(float4*)(fout + (size_t)gwB * 128 + ql * 8) = p0;
                *(float4*)(fout + (size_t)gwB * 128 + ql * 8 + 4) = p1;
            }
        }
    }
}

// Pack W12 into MFMA B-fragment order, bf16 hi + lo residual.
__global__ void k_wpack(const float* __restrict__ w12,
                        ushort* __restrict__ wph, ushort* __restrict__ wpl) {
    int idx = blockIdx.x * 256 + threadIdx.x;  // 0..2047
    int lane = idx & 63;
    int kb = (idx >> 6) & 3;
    int nt = idx >> 8;
    int n = nt * 16 + (lane & 15);
    int k0 = kb * 32 + (lane >> 4) * 8;
    ushort h[8], l[8];
#pragma unroll
    for (int i = 0; i < 8; ++i) {
        float f = w12[(k0 + i) * 128 + n];
        h[i] = bf16rn(f);
        l[i] = bf16rn(f - bf16tof(h[i]));
    }
    uint4 oh, ol;
    oh.x = (uint)h[0] | ((uint)h[1] << 16);
    oh.y = (uint)h[2] | ((uint)h[3] << 16);
    oh.z = (uint)h[4] | ((uint)h[5] << 16);
    oh.w = (uint)h[6] | ((uint)h[7] << 16);
    ol.x = (uint)l[0] | ((uint)l[1] << 16);
    ol.y = (uint)l[2] | ((uint)l[3] << 16);
    ol.z = (uint)l[4] | ((uint)l[5] << 16);
    ol.w = (uint)l[6] | ((uint)l[7] << 16);
    ((uint4*)wph)[idx] = oh;
    ((uint4*)wpl)[idx] = ol;
}

// out = relu( X @ W12 + svec ⊗ cvec + b2 ) — MFMA bf16 split-precision.
__launch_bounds__(256)
__global__ void k_gemm_mfma(const float* __restrict__ X,
                            const ushort* __restrict__ wph, const ushort* __restrict__ wpl,
                            const float* __restrict__ svec, const float* __restrict__ cvec,
                            const float* __restrict__ b2, float* __restrict__ out, int N) {
    __shared__ uint4 wsh[2048];  // 32 KB
    __shared__ uint4 wsl[2048];  // 32 KB
    int tid = threadIdx.x;
    int lane = tid & 63;
    int wv = tid >> 6;
    int row0 = blockIdx.x * 128;

#pragma unroll
    for (int it = 0; it < 8; ++it) {
        wsh[it * 256 + tid] = ((const uint4*)wph)[it * 256 + tid];
        wsl[it * 256 + tid] = ((const uint4*)wpl)[it * 256 + tid];
    }

    bf16x8 ah[2][4], al[2][4];
#pragma unroll
    for (int s = 0; s < 2; ++s) {
#pragma unroll
        for (int kb = 0; kb < 4; ++kb) {
            int row = row0 + wv * 32 + s * 16 + (lane & 15);
            int kbase = kb * 32 + (lane >> 4) * 8;
            float f[8];
            if (row < N) {
                float4 a = *(const float4*)(X + (size_t)row * 128 + kbase);
                float4 b = *(const float4*)(X + (size_t)row * 128 + kbase + 4);
                f[0] = a.x; f[1] = a.y; f[2] = a.z; f[3] = a.w;
                f[4] = b.x; f[5] = b.y; f[6] = b.z; f[7] = b.w;
            } else {
#pragma unroll
                for (int i = 0; i < 8; ++i) f[i] = 0.f;
            }
            bf16x8 hh, ll;
#pragma unroll
            for (int i = 0; i < 8; ++i) {
                ushort h = bf16rn(f[i]);
                hh[i] = (short)h;
                ll[i] = (short)bf16rn(f[i] - bf16tof(h));
            }
            ah[s][kb] = hh;
            al[s][kb] = ll;
        }
    }
    __syncthreads();

    f32x4 acc[2][8];
#pragma unroll
    for (int s = 0; s < 2; ++s)
#pragma unroll
        for (int nt = 0; nt < 8; ++nt) acc[s][nt] = (f32x4)(0.f);

#pragma unroll
    for (int nt = 0; nt < 8; ++nt) {
#pragma unroll
        for (int kb = 0; kb < 4; ++kb) {
            uint4 rh = wsh[(nt * 4 + kb) * 64 + lane];
            uint4 rl = wsl[(nt * 4 + kb) * 64 + lane];
            bf16x8 bh = __builtin_bit_cast(bf16x8, rh);
            bf16x8 bl = __builtin_bit_cast(bf16x8, rl);
            acc[0][nt] = __builtin_amdgcn_mfma_f32_16x16x32_bf16(ah[0][kb], bh, acc[0][nt], 0, 0, 0);
            acc[0][nt] = __builtin_amdgcn_mfma_f32_16x16x32_bf16(al[0][kb], bh, acc[0][nt], 0, 0, 0);
            acc[0][nt] = __builtin_amdgcn_mfma_f32_16x16x32_bf16(ah[0][kb], bl, acc[0][nt], 0, 0, 0);
            acc[1][nt] = __builtin_amdgcn_mfma_f32_16x16x32_bf16(ah[1][kb], bh, acc[1][nt], 0, 0, 0);
            acc[1][nt] = __builtin_amdgcn_mfma_f32_16x16x32_bf16(al[1][kb], bh, acc[1][nt], 0, 0, 0);
            acc[1][nt] = __builtin_amdgcn_mfma_f32_16x16x32_bf16(ah[1][kb], bl, acc[1][nt], 0, 0, 0);
        }
    }

    float cv[8], bv[8];
#pragma unroll
    for (int nt = 0; nt < 8; ++nt) {
        cv[nt] = cvec[nt * 16 + (lane & 15)];
        bv[nt] = b2[nt * 16 + (lane & 15)];
    }
#pragma unroll
    for (int s = 0; s < 2; ++s) {
#pragma unroll
        for (int r = 0; r < 4; ++r) {
            int row = row0 + wv * 32 + s * 16 + (lane >> 4) * 4 + r;
            if (row < N) {
                float sv = svec[row];
#pragma unroll
                for (int nt = 0; nt < 8; ++nt) {
                    float o = fmaxf(acc[s][nt][r] + sv * cv[nt] + bv[nt], 0.f);
                    out[(size_t)row * 128 + nt * 16 + (lane & 15)] = o;
                }
            }
        }
    }
}

extern "C" void kernel_launch(void* const* d_in, const int* in_sizes, int n_in,
                              void* d_out, int out_size, void* d_ws, size_t ws_size,
                              hipStream_t stream) {
    const float* x  = (const float*)d_in[0];
    const int*   ei = (const int*)d_in[1];
    const float* W1 = (const float*)d_in[2];
    const float* b1 = (const float*)d_in[3];
    const float* W2 = (const float*)d_in[4];
    const float* b2 = (const float*)d_in[5];
    float* out = (float*)d_out;

    int N = in_sizes[0] / 128;
    int E = in_sizes[1] / 2;
    const int* srcE = ei;
    const int* dstE = ei + E;

    int nbins = (N + 511) >> BINSH;            // 196 for N=100000 (<=256)
    int nblocksB = (E + EPB - 1) / EPB;        // 391 for E=1.6M
    int L = nbins * nblocksB;                  // 76636
    int nbL = (L + 255) / 256;                 // 300 <= 512

    char* w = (char*)d_ws;
    size_t off = 0;
    auto alloc = [&](size_t bytes) {
        void* p = w + off;
        off = WS_ALIGN(off + bytes);
        return p;
    };
    ushort* xh    = (ushort*)alloc((size_t)N * 256);
    ushort* t1h   = (ushort*)alloc((size_t)N * 256);   // part aliases here early
    int*   csr    = (int*)alloc((size_t)E * 4);
    int*   hist   = (int*)alloc((size_t)L * 4);
    int*   hists  = (int*)alloc((size_t)L * 4);
    int*   bsums  = (int*)alloc(4096);
    int*   offs   = (int*)alloc((size_t)(N + 1) * 4);
    float* dinv   = (float*)alloc((size_t)N * 4);
    float* svec   = (float*)alloc((size_t)N * 4);
    float* w12    = (float*)alloc(128 * 128 * 4);
    ushort* wph   = (ushort*)alloc(128 * 128 * 2);
    ushort* wpl   = (ushort*)alloc(128 * 128 * 2);
    float* cvec   = (float*)alloc(128 * 4);
    (void)ws_size; (void)n_in; (void)out_size;

    uint* part = (uint*)t1h;  // E*4 <= N*256; dead before t1h is written

    // atomic-free CSR build
    k_hist<<<nblocksB, 256, 0, stream>>>(srcE, dstE, hist, E, N, nbins, nblocksB);
    k_scanA<<<nbL, 256, 0, stream>>>(hist, hists, bsums, L);
    k_scan2<<<1, 512, 0, stream>>>(bsums, nbL);
    k_scanB<<<nbL, 256, 0, stream>>>(hists, bsums, L);
    k_part<<<nblocksB, 256, 0, stream>>>(srcE, dstE, hists, part, E, N, nbins, nblocksB);
    k_bin<<<nbins, 256, 0, stream>>>(part, hists, hist, nbins, nblocksB, N,
                                     csr, offs, dinv);
    // pre-scaled x->f16 + w12 + cvec (needs dinv)
    k_conv_w12<<<512 + 65, 256, 0, stream>>>(x, dinv, xh, N, W1, b1, W2, w12, cvec, 512);
    // pass 1: t1h = f16(dinv^2 * sum(xh)) + svec   (part is dead now)
    k_aggq<1><<<(N + 7) / 8, 256, 0, stream>>>(xh, dinv, nullptr, t1h, svec,
                                               offs, csr, N);
    // pass 2: t2 = f32(dinv * sum(t1h)) -> d_out as scratch
    k_aggq<0><<<(N + 7) / 8, 256, 0, stream>>>(t1h, dinv, out, nullptr, nullptr,
                                               offs, csr, N);
    k_wpack<<<8, 256, 0, stream>>>(w12, wph, wpl);
    // out = relu(t2 @ W12 + svec ⊗ cvec + b2), MFMA, in-place on d_out
    k_gemm_mfma<<<(N + 127) / 128, 256, 0, stream>>>(out, wph, wpl, svec, cvec, b2, out, N);
}

// Round 15
// 222.861 us; speedup vs baseline: 1.2734x; 1.0312x over previous
//
#include <hip/hip_runtime.h>

// GCN 2-layer fused:  out = relu( A·(A·x)·(W1@W2) + (A·1)⊗(b1ᵀW2) + b2 )
// A = D^-1/2 (Adj + I) D^-1/2.
// CSR built ATOMIC-FREE via 2-level binning (hist -> scan -> part -> bin).
// Aggregation gathers f16 rows, two nodes per wave; pass 1 weighted
// (bpermuted dinv), outputs di^2-prescaled t1h; pass 2 pure-sum.
// conv/w12/cvec ride k_hist; wpack rides k_part. 8 launches total.
// Final GEMM: MFMA bf16 split-precision, in-place on d_out.
// All __shfl executed unconditionally (exec-masked ds_bpermute undefined).

#define WS_ALIGN(x) (((x) + 255) & ~(size_t)255)
#define BINSH 9                 // bin = dst >> 9 (512 dsts per bin)
#define EPB 4096                // edges per block in hist/part

typedef __attribute__((ext_vector_type(8))) short bf16x8;
typedef __attribute__((ext_vector_type(4))) float f32x4;
typedef _Float16 f16x8 __attribute__((ext_vector_type(8)));
typedef _Float16 f16x4 __attribute__((ext_vector_type(4)));

__device__ inline ushort bf16rn(float f) {
    uint u = __float_as_uint(f);
    u = (u + 0x7FFFu + ((u >> 16) & 1u)) >> 16;
    return (ushort)u;
}
__device__ inline float bf16tof(ushort h) {
    return __uint_as_float(((uint)h) << 16);
}

// blocks [0,hb): per-block LDS histogram of dst bins;
// [hb,hb+cb): x -> f16 (unscaled); [hb+cb,+64): w12 = W1@W2; last: cvec.
__global__ void k_hist_fused(const int* __restrict__ src, const int* __restrict__ dst,
                             int* __restrict__ hist, int E, int N, int nbins, int hb,
                             const float* __restrict__ x, ushort* __restrict__ xh,
                             const float* __restrict__ W1, const float* __restrict__ b1,
                             const float* __restrict__ W2,
                             float* __restrict__ w12, float* __restrict__ cvec, int cb) {
    int bid = blockIdx.x;
    int tid = threadIdx.x;
    if (bid < hb) {
        __shared__ int h[256];
        h[tid] = 0;
        __syncthreads();
        int e0 = bid * EPB;
#pragma unroll
        for (int i = 0; i < EPB / 256; ++i) {
            int e = e0 + i * 256 + tid;
            if (e < E) {
                int d = dst[e];
                int s = src[e];
                if ((unsigned)d < (unsigned)N && (unsigned)s < (unsigned)N)
                    atomicAdd(&h[d >> BINSH], 1);
            }
        }
        __syncthreads();
        if (tid < nbins) hist[tid * hb + bid] = h[tid];
    } else if (bid < hb + cb) {
        int t = (bid - hb) * 256 + tid;
        int stride = cb * 256;
        int n4 = N * 32;   // float4's
        for (int i = t; i < n4; i += stride) {
            float4 v = ((const float4*)x)[i];
            f16x4 hh;
            hh[0] = (_Float16)v.x;
            hh[1] = (_Float16)v.y;
            hh[2] = (_Float16)v.z;
            hh[3] = (_Float16)v.w;
            ((uint2*)xh)[i] = __builtin_bit_cast(uint2, hh);
        }
    } else if (bid < hb + cb + 64) {
        int idx = (bid - hb - cb) * 256 + tid;  // 0..16383
        int i = idx >> 7, j = idx & 127;
        float s = 0.f;
#pragma unroll 8
        for (int k = 0; k < 128; ++k) s = fmaf(W1[i * 128 + k], W2[k * 128 + j], s);
        w12[idx] = s;
    } else {
        int j = tid;
        if (j < 128) {
            float s = 0.f;
#pragma unroll 8
            for (int k = 0; k < 128; ++k) s = fmaf(b1[k], W2[k * 128 + j], s);
            cvec[j] = s;
        }
    }
}

// Exclusive scan (block-local) of hist[L] -> hists, block sums to bsums.
// Consumers add bsums[i>>8] inline (no scanB pass).
__global__ void k_scanA(const int* __restrict__ in, int* __restrict__ outv,
                        int* __restrict__ bsums, int L) {
    __shared__ int sh[256];
    int i = blockIdx.x * 256 + threadIdx.x;
    int v = (i < L) ? in[i] : 0;
    sh[threadIdx.x] = v;
    __syncthreads();
    for (int off = 1; off < 256; off <<= 1) {
        int t = (threadIdx.x >= off) ? sh[threadIdx.x - off] : 0;
        __syncthreads();
        sh[threadIdx.x] += t;
        __syncthreads();
    }
    if (i < L) outv[i] = sh[threadIdx.x] - v;
    if (threadIdx.x == 255) bsums[blockIdx.x] = sh[255];
}

__global__ void k_scan2(int* __restrict__ bsums, int nb) {
    __shared__ int sh[512];
    int tid = threadIdx.x;
    int v = (tid < nb) ? bsums[tid] : 0;
    sh[tid] = v;
    __syncthreads();
    for (int off = 1; off < 512; off <<= 1) {
        int t = (tid >= off) ? sh[tid - off] : 0;
        __syncthreads();
        sh[tid] += t;
        __syncthreads();
    }
    if (tid < nb) bsums[tid] = sh[tid] - v;
}

// blocks [0,pb): partition edges into (bin,block) windows (LDS cursors,
// fire-and-forget global writes); payload = (dlocal<<23)|src.
// blocks [pb,pb+8): pack W12 into MFMA B-fragment order (bf16 hi+lo).
__global__ void k_part_fused(const int* __restrict__ src, const int* __restrict__ dst,
                             const int* __restrict__ hists, const int* __restrict__ bsums,
                             uint* __restrict__ part, int E, int N, int nbins, int pb,
                             const float* __restrict__ w12,
                             ushort* __restrict__ wph, ushort* __restrict__ wpl) {
    int bid = blockIdx.x;
    int tid = threadIdx.x;
    if (bid < pb) {
        __shared__ int cur[256];
        if (tid < nbins) {
            int fi = tid * pb + bid;
            cur[tid] = hists[fi] + bsums[fi >> 8];
        }
        __syncthreads();
        int e0 = bid * EPB;
#pragma unroll
        for (int i = 0; i < EPB / 256; ++i) {
            int e = e0 + i * 256 + tid;
            if (e < E) {
                int d = dst[e];
                int s = src[e];
                if ((unsigned)d < (unsigned)N && (unsigned)s < (unsigned)N) {
                    int pos = atomicAdd(&cur[d >> BINSH], 1);
                    part[pos] = (uint)s | ((uint)(d & 511) << 23);
                }
            }
        }
    } else {
        int idx = (bid - pb) * 256 + tid;  // 0..2047
        int lane = idx & 63;
        int kb = (idx >> 6) & 3;
        int nt = idx >> 8;
        int n = nt * 16 + (lane & 15);
        int k0 = kb * 32 + (lane >> 4) * 8;
        ushort h[8], l[8];
#pragma unroll
        for (int i = 0; i < 8; ++i) {
            float f = w12[(k0 + i) * 128 + n];
            h[i] = bf16rn(f);
            l[i] = bf16rn(f - bf16tof(h[i]));
        }
        uint4 oh, ol;
        oh.x = (uint)h[0] | ((uint)h[1] << 16);
        oh.y = (uint)h[2] | ((uint)h[3] << 16);
        oh.z = (uint)h[4] | ((uint)h[5] << 16);
        oh.w = (uint)h[6] | ((uint)h[7] << 16);
        ol.x = (uint)l[0] | ((uint)l[1] << 16);
        ol.y = (uint)l[2] | ((uint)l[3] << 16);
        ol.z = (uint)l[4] | ((uint)l[5] << 16);
        ol.w = (uint)l[6] | ((uint)l[7] << 16);
        ((uint4*)wph)[idx] = oh;
        ((uint4*)wpl)[idx] = ol;
    }
}

// One block per bin: count its 512 dsts (LDS), scan, emit offs/dinv, then
// fill csr via LDS-atomic rank. Scanned histogram read with inline bsums.
__global__ void k_bin(const uint* __restrict__ part, const int* __restrict__ hists,
                      const int* __restrict__ bsums, const int* __restrict__ hist,
                      int nbins, int nblocksB, int N,
                      int* __restrict__ csr, int* __restrict__ offs,
                      float* __restrict__ dinv) {
    __shared__ int cnt[512];
    __shared__ int loff[512];
    __shared__ int ps[256];
    int b = blockIdx.x;
    int tid = threadIdx.x;
    int fi0 = b * nblocksB;
    int start = hists[fi0] + bsums[fi0 >> 8];
    int last = nbins * nblocksB - 1;
    int end;
    if (b + 1 < nbins) {
        int fi1 = (b + 1) * nblocksB;
        end = hists[fi1] + bsums[fi1 >> 8];
    } else {
        end = hists[last] + bsums[last >> 8] + hist[last];
    }

    cnt[tid] = 0;
    cnt[tid + 256] = 0;
    __syncthreads();
    for (int i = start + tid; i < end; i += 256)
        atomicAdd(&cnt[part[i] >> 23], 1);
    __syncthreads();

    // exclusive scan of cnt[512]: pair-sums then 256-wide Hillis-Steele
    int a0 = cnt[2 * tid], a1 = cnt[2 * tid + 1];
    ps[tid] = a0 + a1;
    __syncthreads();
    for (int off = 1; off < 256; off <<= 1) {
        int t = (tid >= off) ? ps[tid - off] : 0;
        __syncthreads();
        ps[tid] += t;
        __syncthreads();
    }
    int excl = ps[tid] - (a0 + a1);
    loff[2 * tid] = excl;
    loff[2 * tid + 1] = excl + a0;
    __syncthreads();

    int d0 = b << BINSH;
#pragma unroll
    for (int h = 0; h < 2; ++h) {
        int k = tid + h * 256;
        int d = d0 + k;
        if (d < N) {
            offs[d] = start + loff[k];
            dinv[d] = rsqrtf((float)(cnt[k] + 1));
        }
    }
    if (b == nbins - 1 && tid == 0) offs[N] = end;
    __syncthreads();

    for (int i = start + tid; i < end; i += 256) {
        uint p = part[i];
        int pos = atomicAdd(&loff[p >> 23], 1);
        csr[start + pos] = (int)(p & 0x7FFFFFu);
    }
}

// Aggregation over f16 rows; TWO nodes per wave (A=2w, B=2w+1).
// WRITE_Q=1 (pass 1): weighted gather (bpermuted dinv[s]); out rows =
//   f16(di^2 * (di*x_self + sum dj*x_j)) [prescaled for pass 2]; svec.
// WRITE_Q=0 (pass 2): pure sum of prescaled rows; out = f32(di * sum).
template <int WRITE_Q>
__launch_bounds__(256)
__global__ void k_aggq(const ushort* __restrict__ xh, const float* __restrict__ dinv,
                       float* __restrict__ fout, ushort* __restrict__ qout,
                       float* __restrict__ svec,
                       const int* __restrict__ offs, const int* __restrict__ csr, int N) {
    int wid = (int)((blockIdx.x * (size_t)blockDim.x + threadIdx.x) >> 6);
    int lane = threadIdx.x & 63;
    int gwA = 2 * wid, gwB = 2 * wid + 1;
    if (gwA >= N) return;
    bool vB = (gwB < N);
    int q = lane >> 4, ql = lane & 15;
    float diA = dinv[gwA];
    float diB = vB ? dinv[gwB] : 0.f;
    const uint4* __restrict__ xh4 = (const uint4*)xh;

    float accA[8], accB[8];
#pragma unroll
    for (int j = 0; j < 8; ++j) { accA[j] = 0.f; accB[j] = 0.f; }
    float sdA = 0.f, sdB = 0.f;

    if (q == 0) {  // self terms
        uint4 va = xh4[((size_t)gwA << 4) + ql];
        f16x8 ha = __builtin_bit_cast(f16x8, va);
        float wA = WRITE_Q ? diA : 1.f;   // pass 1: di * x_self; pass 2: row is prescaled
#pragma unroll
        for (int j = 0; j < 8; ++j) accA[j] = wA * (float)ha[j];
        if (vB) {
            uint4 vb = xh4[((size_t)gwB << 4) + ql];
            f16x8 hb = __builtin_bit_cast(f16x8, vb);
            float wB = WRITE_Q ? diB : 1.f;
#pragma unroll
            for (int j = 0; j < 8; ++j) accB[j] = wB * (float)hb[j];
        }
    }

    int s0A = offs[gwA], s1A = offs[gwA + 1];
    int s0B = s1A;
    int s1B = vB ? offs[gwB + 1] : s1A;

    int baseA = s0A, baseB = s0B;
    while (baseA < s1A || baseB < s1B) {
        int cA = s1A - baseA; cA = cA < 0 ? 0 : (cA > 64 ? 64 : cA);
        int cB = s1B - baseB; cB = cB < 0 ? 0 : (cB > 64 ? 64 : cB);
        int sidxA = 0, sidxB = 0;
        float dvA = 0.f, dvB = 0.f;   // padded lanes keep 0
        if (lane < cA) sidxA = csr[baseA + lane];
        if (lane < cB) sidxB = csr[baseB + lane];
        if (WRITE_Q) {
            if (lane < cA) { dvA = dinv[sidxA]; sdA += dvA; }
            if (lane < cB) { dvB = dinv[sidxB]; sdB += dvB; }
        }
        int itA = (cA + 3) >> 2, itB = (cB + 3) >> 2;
        int iters = itA > itB ? itA : itB;
#pragma unroll 2
        for (int i = 0; i < iters; ++i) {
            int t = 4 * i + q;   // t <= 63 always
            // shfls outside divergent guards (all source lanes active)
            int sA = __shfl(sidxA, t);
            int sB = __shfl(sidxB, t);
            float dA = 0.f, dB = 0.f;
            if (WRITE_Q) { dA = __shfl(dvA, t); dB = __shfl(dvB, t); }
            if (t < cA) {
                uint4 v = xh4[((size_t)sA << 4) + ql];
                f16x8 h = __builtin_bit_cast(f16x8, v);
#pragma unroll
                for (int j = 0; j < 8; ++j) {
                    if (WRITE_Q) accA[j] = fmaf(dA, (float)h[j], accA[j]);
                    else         accA[j] += (float)h[j];
                }
            }
            if (t < cB) {
                uint4 v = xh4[((size_t)sB << 4) + ql];
                f16x8 h = __builtin_bit_cast(f16x8, v);
#pragma unroll
                for (int j = 0; j < 8; ++j) {
                    if (WRITE_Q) accB[j] = fmaf(dB, (float)h[j], accB[j]);
                    else         accB[j] += (float)h[j];
                }
            }
        }
        baseA += 64;
        baseB += 64;
    }

#pragma unroll
    for (int j = 0; j < 8; ++j) {
        accA[j] += __shfl_xor(accA[j], 16);
        accA[j] += __shfl_xor(accA[j], 32);
        accB[j] += __shfl_xor(accB[j], 16);
        accB[j] += __shfl_xor(accB[j], 32);
    }

    if (WRITE_Q) {
#pragma unroll
        for (int d = 1; d < 64; d <<= 1) {
            sdA += __shfl_xor(sdA, d);
            sdB += __shfl_xor(sdB, d);
        }
        if (lane == 0) {
            svec[gwA] = diA * (diA + sdA);
            if (vB) svec[gwB] = diB * (diB + sdB);
        }
        if (q == 0) {  // store prescaled: dinv * t1 = di^2 * acc
            float fA = diA * diA, fB = diB * diB;
            f16x8 ha, hb;
#pragma unroll
            for (int j = 0; j < 8; ++j) {
                ha[j] = (_Float16)(fA * accA[j]);
                hb[j] = (_Float16)(fB * accB[j]);
            }
            *(uint4*)(qout + (size_t)gwA * 128 + ql * 8) = __builtin_bit_cast(uint4, ha);
            if (vB) *(uint4*)(qout + (size_t)gwB * 128 + ql * 8) = __builtin_bit_cast(uint4, hb);
        }
    } else {
        if (q == 0) {  // t2 = di * sum, f32
            float4 o0, o1, p0, p1;
            o0.x = diA * accA[0]; o0.y = diA * accA[1]; o0.z = diA * accA[2]; o0.w = diA * accA[3];
            o1.x = diA * accA[4]; o1.y = diA * accA[5]; o1.z = diA * accA[6]; o1.w = diA * accA[7];
            *(float4*)(fout + (size_t)gwA * 128 + ql * 8) = o0;
            *(float4*)(fout + (size_t)gwA * 128 + ql * 8 + 4) = o1;
            if (vB) {
                p0.x = diB * accB[0]; p0.y = diB * accB[1]; p0.z = diB * accB[2]; p0.w = diB * accB[3];
                p1.x = diB * accB[4]; p1.y = diB * accB[5]; p1.z = diB * accB[6]; p1.w = diB * accB[7];
                *(float4*)(fout + (size_t)gwB * 128 + ql * 8) = p0;
                *(float4*)(fout + (size_t)gwB * 128 + ql * 8 + 4) = p1;
            }
        }
    }
}

// out = relu( X @ W12 + svec ⊗ cvec + b2 ) — MFMA bf16 split-precision
// (X@W = Xhi·Whi + Xlo·Whi + Xhi·Wlo). 256 threads / 4 waves; block covers
// 128 rows; wave owns 32 rows x all 8 col-tiles. W fragments in LDS (64KB).
// In-place safe (X == out): all A loads precede all stores within a block.
__launch_bounds__(256)
__global__ void k_gemm_mfma(const float* __restrict__ X,
                            const ushort* __restrict__ wph, const ushort* __restrict__ wpl,
                            const float* __restrict__ svec, const float* __restrict__ cvec,
                            const float* __restrict__ b2, float* __restrict__ out, int N) {
    __shared__ uint4 wsh[2048];  // 32 KB
    __shared__ uint4 wsl[2048];  // 32 KB
    int tid = threadIdx.x;
    int lane = tid & 63;
    int wv = tid >> 6;
    int row0 = blockIdx.x * 128;

#pragma unroll
    for (int it = 0; it < 8; ++it) {
        wsh[it * 256 + tid] = ((const uint4*)wph)[it * 256 + tid];
        wsl[it * 256 + tid] = ((const uint4*)wpl)[it * 256 + tid];
    }

    bf16x8 ah[2][4], al[2][4];
#pragma unroll
    for (int s = 0; s < 2; ++s) {
#pragma unroll
        for (int kb = 0; kb < 4; ++kb) {
            int row = row0 + wv * 32 + s * 16 + (lane & 15);
            int kbase = kb * 32 + (lane >> 4) * 8;
            float f[8];
            if (row < N) {
                float4 a = *(const float4*)(X + (size_t)row * 128 + kbase);
                float4 b = *(const float4*)(X + (size_t)row * 128 + kbase + 4);
                f[0] = a.x; f[1] = a.y; f[2] = a.z; f[3] = a.w;
                f[4] = b.x; f[5] = b.y; f[6] = b.z; f[7] = b.w;
            } else {
#pragma unroll
                for (int i = 0; i < 8; ++i) f[i] = 0.f;
            }
            bf16x8 hh, ll;
#pragma unroll
            for (int i = 0; i < 8; ++i) {
                ushort h = bf16rn(f[i]);
                hh[i] = (short)h;
                ll[i] = (short)bf16rn(f[i] - bf16tof(h));
            }
            ah[s][kb] = hh;
            al[s][kb] = ll;
        }
    }
    __syncthreads();

    f32x4 acc[2][8];
#pragma unroll
    for (int s = 0; s < 2; ++s)
#pragma unroll
        for (int nt = 0; nt < 8; ++nt) acc[s][nt] = (f32x4)(0.f);

#pragma unroll
    for (int nt = 0; nt < 8; ++nt) {
#pragma unroll
        for (int kb = 0; kb < 4; ++kb) {
            uint4 rh = wsh[(nt * 4 + kb) * 64 + lane];
            uint4 rl = wsl[(nt * 4 + kb) * 64 + lane];
            bf16x8 bh = __builtin_bit_cast(bf16x8, rh);
            bf16x8 bl = __builtin_bit_cast(bf16x8, rl);
            acc[0][nt] = __builtin_amdgcn_mfma_f32_16x16x32_bf16(ah[0][kb], bh, acc[0][nt], 0, 0, 0);
            acc[0][nt] = __builtin_amdgcn_mfma_f32_16x16x32_bf16(al[0][kb], bh, acc[0][nt], 0, 0, 0);
            acc[0][nt] = __builtin_amdgcn_mfma_f32_16x16x32_bf16(ah[0][kb], bl, acc[0][nt], 0, 0, 0);
            acc[1][nt] = __builtin_amdgcn_mfma_f32_16x16x32_bf16(ah[1][kb], bh, acc[1][nt], 0, 0, 0);
            acc[1][nt] = __builtin_amdgcn_mfma_f32_16x16x32_bf16(al[1][kb], bh, acc[1][nt], 0, 0, 0);
            acc[1][nt] = __builtin_amdgcn_mfma_f32_16x16x32_bf16(ah[1][kb], bl, acc[1][nt], 0, 0, 0);
        }
    }

    float cv[8], bv[8];
#pragma unroll
    for (int nt = 0; nt < 8; ++nt) {
        cv[nt] = cvec[nt * 16 + (lane & 15)];
        bv[nt] = b2[nt * 16 + (lane & 15)];
    }
#pragma unroll
    for (int s = 0; s < 2; ++s) {
#pragma unroll
        for (int r = 0; r < 4; ++r) {
            int row = row0 + wv * 32 + s * 16 + (lane >> 4) * 4 + r;
            if (row < N) {
                float sv = svec[row];
#pragma unroll
                for (int nt = 0; nt < 8; ++nt) {
                    float o = fmaxf(acc[s][nt][r] + sv * cv[nt] + bv[nt], 0.f);
                    out[(size_t)row * 128 + nt * 16 + (lane & 15)] = o;
                }
            }
        }
    }
}

extern "C" void kernel_launch(void* const* d_in, const int* in_sizes, int n_in,
                              void* d_out, int out_size, void* d_ws, size_t ws_size,
                              hipStream_t stream) {
    const float* x  = (const float*)d_in[0];
    const int*   ei = (const int*)d_in[1];
    const float* W1 = (const float*)d_in[2];
    const float* b1 = (const float*)d_in[3];
    const float* W2 = (const float*)d_in[4];
    const float* b2 = (const float*)d_in[5];
    float* out = (float*)d_out;

    int N = in_sizes[0] / 128;
    int E = in_sizes[1] / 2;
    const int* srcE = ei;
    const int* dstE = ei + E;

    int nbins = (N + 511) >> BINSH;            // 196 for N=100000 (<=256)
    int nblocksB = (E + EPB - 1) / EPB;        // 391 for E=1.6M
    int L = nbins * nblocksB;                  // 76636
    int nbL = (L + 255) / 256;                 // 300 <= 512

    char* w = (char*)d_ws;
    size_t off = 0;
    auto alloc = [&](size_t bytes) {
        void* p = w + off;
        off = WS_ALIGN(off + bytes);
        return p;
    };
    ushort* xh    = (ushort*)alloc((size_t)N * 256);
    ushort* t1h   = (ushort*)alloc((size_t)N * 256);   // part aliases here early
    int*   csr    = (int*)alloc((size_t)E * 4);
    int*   hist   = (int*)alloc((size_t)L * 4);
    int*   hists  = (int*)alloc((size_t)L * 4);
    int*   bsums  = (int*)alloc(4096);
    int*   offs   = (int*)alloc((size_t)(N + 1) * 4);
    float* dinv   = (float*)alloc((size_t)N * 4);
    float* svec   = (float*)alloc((size_t)N * 4);
    float* w12    = (float*)alloc(128 * 128 * 4);
    ushort* wph   = (ushort*)alloc(128 * 128 * 2);
    ushort* wpl   = (ushort*)alloc(128 * 128 * 2);
    float* cvec   = (float*)alloc(128 * 4);
    (void)ws_size; (void)n_in; (void)out_size;

    uint* part = (uint*)t1h;  // E*4 <= N*256; dead before t1h is written

    int cb = 512;  // conversion rider blocks
    // 1: hist + conv(f16) + w12 + cvec
    k_hist_fused<<<nblocksB + cb + 65, 256, 0, stream>>>(srcE, dstE, hist, E, N, nbins,
                                                         nblocksB, x, xh, W1, b1, W2,
                                                         w12, cvec, cb);
    // 2-3: scan histogram (block-local + block-sum scan; consumers add inline)
    k_scanA<<<nbL, 256, 0, stream>>>(hist, hists, bsums, L);
    k_scan2<<<1, 512, 0, stream>>>(bsums, nbL);
    // 4: partition + wpack rider
    k_part_fused<<<nblocksB + 8, 256, 0, stream>>>(srcE, dstE, hists, bsums, part,
                                                   E, N, nbins, nblocksB, w12, wph, wpl);
    // 5: per-bin count/scan/fill -> csr, offs, dinv
    k_bin<<<nbins, 256, 0, stream>>>(part, hists, bsums, hist, nbins, nblocksB, N,
                                     csr, offs, dinv);
    // 6: pass 1: t1h = f16(di^2*(di*x_self + sum dj*x_j)) + svec  (part dead now)
    k_aggq<1><<<(N + 7) / 8, 256, 0, stream>>>(xh, dinv, nullptr, t1h, svec,
                                               offs, csr, N);
    // 7: pass 2: t2 = f32(di * sum(t1h)) -> d_out as scratch
    k_aggq<0><<<(N + 7) / 8, 256, 0, stream>>>(t1h, dinv, out, nullptr, nullptr,
                                               offs, csr, N);
    // 8: out = relu(t2 @ W12 + svec ⊗ cvec + b2), MFMA, in-place on d_out
    k_gemm_mfma<<<(N + 127) / 128, 256, 0, stream>>>(out, wph, wpl, svec, cvec, b2, out, N);
}

// Round 16
// 217.188 us; speedup vs baseline: 1.3066x; 1.0261x over previous
//
#include <hip/hip_runtime.h>

// GCN 2-layer fused:  out = relu( A·(A·x)·(W1@W2) + (A·1)⊗(b1ᵀW2) + b2 )
// A = D^-1/2 (Adj + I) D^-1/2.
// CSR built ATOMIC-FREE via 2-level binning (hist -> scan -> part -> bin).
// Aggregation gathers f16 rows, two nodes per wave; pass 1 weighted
// (bpermuted dinv), outputs di^2-prescaled f16 t1h + svec; pass 2 pure-sum,
// outputs f16 t2h (halves the t2 round-trip vs f32).
// conv/w12/cvec ride k_hist; wpack rides k_part. 8 launches total.
// Final GEMM: MFMA bf16 split-precision from f16 A (exact hi/lo split).
// All __shfl executed unconditionally (exec-masked ds_bpermute undefined).

#define WS_ALIGN(x) (((x) + 255) & ~(size_t)255)
#define BINSH 9                 // bin = dst >> 9 (512 dsts per bin)
#define EPB 4096                // edges per block in hist/part

typedef __attribute__((ext_vector_type(8))) short bf16x8;
typedef __attribute__((ext_vector_type(4))) float f32x4;
typedef _Float16 f16x8 __attribute__((ext_vector_type(8)));
typedef _Float16 f16x4 __attribute__((ext_vector_type(4)));

__device__ inline ushort bf16rn(float f) {
    uint u = __float_as_uint(f);
    u = (u + 0x7FFFu + ((u >> 16) & 1u)) >> 16;
    return (ushort)u;
}
__device__ inline float bf16tof(ushort h) {
    return __uint_as_float(((uint)h) << 16);
}

// blocks [0,hb): per-block LDS histogram of dst bins;
// [hb,hb+cb): x -> f16 (unscaled); [hb+cb,+64): w12 = W1@W2; last: cvec.
__global__ void k_hist_fused(const int* __restrict__ src, const int* __restrict__ dst,
                             int* __restrict__ hist, int E, int N, int nbins, int hb,
                             const float* __restrict__ x, ushort* __restrict__ xh,
                             const float* __restrict__ W1, const float* __restrict__ b1,
                             const float* __restrict__ W2,
                             float* __restrict__ w12, float* __restrict__ cvec, int cb) {
    int bid = blockIdx.x;
    int tid = threadIdx.x;
    if (bid < hb) {
        __shared__ int h[256];
        h[tid] = 0;
        __syncthreads();
        int e0 = bid * EPB;
#pragma unroll
        for (int i = 0; i < EPB / 256; ++i) {
            int e = e0 + i * 256 + tid;
            if (e < E) {
                int d = dst[e];
                int s = src[e];
                if ((unsigned)d < (unsigned)N && (unsigned)s < (unsigned)N)
                    atomicAdd(&h[d >> BINSH], 1);
            }
        }
        __syncthreads();
        if (tid < nbins) hist[tid * hb + bid] = h[tid];
    } else if (bid < hb + cb) {
        int t = (bid - hb) * 256 + tid;
        int stride = cb * 256;
        int n4 = N * 32;   // float4's
        for (int i = t; i < n4; i += stride) {
            float4 v = ((const float4*)x)[i];
            f16x4 hh;
            hh[0] = (_Float16)v.x;
            hh[1] = (_Float16)v.y;
            hh[2] = (_Float16)v.z;
            hh[3] = (_Float16)v.w;
            ((uint2*)xh)[i] = __builtin_bit_cast(uint2, hh);
        }
    } else if (bid < hb + cb + 64) {
        int idx = (bid - hb - cb) * 256 + tid;  // 0..16383
        int i = idx >> 7, j = idx & 127;
        float s = 0.f;
#pragma unroll 8
        for (int k = 0; k < 128; ++k) s = fmaf(W1[i * 128 + k], W2[k * 128 + j], s);
        w12[idx] = s;
    } else {
        int j = tid;
        if (j < 128) {
            float s = 0.f;
#pragma unroll 8
            for (int k = 0; k < 128; ++k) s = fmaf(b1[k], W2[k * 128 + j], s);
            cvec[j] = s;
        }
    }
}

// Exclusive scan (block-local) of hist[L] -> hists, block sums to bsums.
// Consumers add bsums[i>>8] inline (no scanB pass).
__global__ void k_scanA(const int* __restrict__ in, int* __restrict__ outv,
                        int* __restrict__ bsums, int L) {
    __shared__ int sh[256];
    int i = blockIdx.x * 256 + threadIdx.x;
    int v = (i < L) ? in[i] : 0;
    sh[threadIdx.x] = v;
    __syncthreads();
    for (int off = 1; off < 256; off <<= 1) {
        int t = (threadIdx.x >= off) ? sh[threadIdx.x - off] : 0;
        __syncthreads();
        sh[threadIdx.x] += t;
        __syncthreads();
    }
    if (i < L) outv[i] = sh[threadIdx.x] - v;
    if (threadIdx.x == 255) bsums[blockIdx.x] = sh[255];
}

__global__ void k_scan2(int* __restrict__ bsums, int nb) {
    __shared__ int sh[512];
    int tid = threadIdx.x;
    int v = (tid < nb) ? bsums[tid] : 0;
    sh[tid] = v;
    __syncthreads();
    for (int off = 1; off < 512; off <<= 1) {
        int t = (tid >= off) ? sh[tid - off] : 0;
        __syncthreads();
        sh[tid] += t;
        __syncthreads();
    }
    if (tid < nb) bsums[tid] = sh[tid] - v;
}

// blocks [0,pb): partition edges into (bin,block) windows (LDS cursors,
// fire-and-forget global writes); payload = (dlocal<<23)|src.
// blocks [pb,pb+8): pack W12 into MFMA B-fragment order (bf16 hi+lo).
__global__ void k_part_fused(const int* __restrict__ src, const int* __restrict__ dst,
                             const int* __restrict__ hists, const int* __restrict__ bsums,
                             uint* __restrict__ part, int E, int N, int nbins, int pb,
                             const float* __restrict__ w12,
                             ushort* __restrict__ wph, ushort* __restrict__ wpl) {
    int bid = blockIdx.x;
    int tid = threadIdx.x;
    if (bid < pb) {
        __shared__ int cur[256];
        if (tid < nbins) {
            int fi = tid * pb + bid;
            cur[tid] = hists[fi] + bsums[fi >> 8];
        }
        __syncthreads();
        int e0 = bid * EPB;
#pragma unroll
        for (int i = 0; i < EPB / 256; ++i) {
            int e = e0 + i * 256 + tid;
            if (e < E) {
                int d = dst[e];
                int s = src[e];
                if ((unsigned)d < (unsigned)N && (unsigned)s < (unsigned)N) {
                    int pos = atomicAdd(&cur[d >> BINSH], 1);
                    part[pos] = (uint)s | ((uint)(d & 511) << 23);
                }
            }
        }
    } else {
        int idx = (bid - pb) * 256 + tid;  // 0..2047
        int lane = idx & 63;
        int kb = (idx >> 6) & 3;
        int nt = idx >> 8;
        int n = nt * 16 + (lane & 15);
        int k0 = kb * 32 + (lane >> 4) * 8;
        ushort h[8], l[8];
#pragma unroll
        for (int i = 0; i < 8; ++i) {
            float f = w12[(k0 + i) * 128 + n];
            h[i] = bf16rn(f);
            l[i] = bf16rn(f - bf16tof(h[i]));
        }
        uint4 oh, ol;
        oh.x = (uint)h[0] | ((uint)h[1] << 16);
        oh.y = (uint)h[2] | ((uint)h[3] << 16);
        oh.z = (uint)h[4] | ((uint)h[5] << 16);
        oh.w = (uint)h[6] | ((uint)h[7] << 16);
        ol.x = (uint)l[0] | ((uint)l[1] << 16);
        ol.y = (uint)l[2] | ((uint)l[3] << 16);
        ol.z = (uint)l[4] | ((uint)l[5] << 16);
        ol.w = (uint)l[6] | ((uint)l[7] << 16);
        ((uint4*)wph)[idx] = oh;
        ((uint4*)wpl)[idx] = ol;
    }
}

// One block per bin: count its 512 dsts (LDS), scan, emit offs/dinv, then
// fill csr via LDS-atomic rank. Scanned histogram read with inline bsums.
__global__ void k_bin(const uint* __restrict__ part, const int* __restrict__ hists,
                      const int* __restrict__ bsums, const int* __restrict__ hist,
                      int nbins, int nblocksB, int N,
                      int* __restrict__ csr, int* __restrict__ offs,
                      float* __restrict__ dinv) {
    __shared__ int cnt[512];
    __shared__ int loff[512];
    __shared__ int ps[256];
    int b = blockIdx.x;
    int tid = threadIdx.x;
    int fi0 = b * nblocksB;
    int start = hists[fi0] + bsums[fi0 >> 8];
    int last = nbins * nblocksB - 1;
    int end;
    if (b + 1 < nbins) {
        int fi1 = (b + 1) * nblocksB;
        end = hists[fi1] + bsums[fi1 >> 8];
    } else {
        end = hists[last] + bsums[last >> 8] + hist[last];
    }

    cnt[tid] = 0;
    cnt[tid + 256] = 0;
    __syncthreads();
    for (int i = start + tid; i < end; i += 256)
        atomicAdd(&cnt[part[i] >> 23], 1);
    __syncthreads();

    // exclusive scan of cnt[512]: pair-sums then 256-wide Hillis-Steele
    int a0 = cnt[2 * tid], a1 = cnt[2 * tid + 1];
    ps[tid] = a0 + a1;
    __syncthreads();
    for (int off = 1; off < 256; off <<= 1) {
        int t = (tid >= off) ? ps[tid - off] : 0;
        __syncthreads();
        ps[tid] += t;
        __syncthreads();
    }
    int excl = ps[tid] - (a0 + a1);
    loff[2 * tid] = excl;
    loff[2 * tid + 1] = excl + a0;
    __syncthreads();

    int d0 = b << BINSH;
#pragma unroll
    for (int h = 0; h < 2; ++h) {
        int k = tid + h * 256;
        int d = d0 + k;
        if (d < N) {
            offs[d] = start + loff[k];
            dinv[d] = rsqrtf((float)(cnt[k] + 1));
        }
    }
    if (b == nbins - 1 && tid == 0) offs[N] = end;
    __syncthreads();

    for (int i = start + tid; i < end; i += 256) {
        uint p = part[i];
        int pos = atomicAdd(&loff[p >> 23], 1);
        csr[start + pos] = (int)(p & 0x7FFFFFu);
    }
}

// Aggregation over f16 rows; TWO nodes per wave (A=2w, B=2w+1).
// PASS1=1: weighted gather (bpermuted dinv[s]); out = f16(di^2*(di*x_self +
//   sum dj*x_j)) [prescaled for pass 2]; svec = di*(di + sum dj).
// PASS1=0: pure sum of prescaled rows; out = f16(di * sum).
template <int PASS1>
__launch_bounds__(256)
__global__ void k_aggq(const ushort* __restrict__ xh, const float* __restrict__ dinv,
                       ushort* __restrict__ qout, float* __restrict__ svec,
                       const int* __restrict__ offs, const int* __restrict__ csr, int N) {
    int wid = (int)((blockIdx.x * (size_t)blockDim.x + threadIdx.x) >> 6);
    int lane = threadIdx.x & 63;
    int gwA = 2 * wid, gwB = 2 * wid + 1;
    if (gwA >= N) return;
    bool vB = (gwB < N);
    int q = lane >> 4, ql = lane & 15;
    float diA = dinv[gwA];
    float diB = vB ? dinv[gwB] : 0.f;
    const uint4* __restrict__ xh4 = (const uint4*)xh;

    float accA[8], accB[8];
#pragma unroll
    for (int j = 0; j < 8; ++j) { accA[j] = 0.f; accB[j] = 0.f; }
    float sdA = 0.f, sdB = 0.f;

    if (q == 0) {  // self terms
        uint4 va = xh4[((size_t)gwA << 4) + ql];
        f16x8 ha = __builtin_bit_cast(f16x8, va);
        float wA = PASS1 ? diA : 1.f;   // pass 2 rows are prescaled
#pragma unroll
        for (int j = 0; j < 8; ++j) accA[j] = wA * (float)ha[j];
        if (vB) {
            uint4 vb = xh4[((size_t)gwB << 4) + ql];
            f16x8 hb = __builtin_bit_cast(f16x8, vb);
            float wB = PASS1 ? diB : 1.f;
#pragma unroll
            for (int j = 0; j < 8; ++j) accB[j] = wB * (float)hb[j];
        }
    }

    int s0A = offs[gwA], s1A = offs[gwA + 1];
    int s0B = s1A;
    int s1B = vB ? offs[gwB + 1] : s1A;

    int baseA = s0A, baseB = s0B;
    while (baseA < s1A || baseB < s1B) {
        int cA = s1A - baseA; cA = cA < 0 ? 0 : (cA > 64 ? 64 : cA);
        int cB = s1B - baseB; cB = cB < 0 ? 0 : (cB > 64 ? 64 : cB);
        int sidxA = 0, sidxB = 0;
        float dvA = 0.f, dvB = 0.f;   // padded lanes keep 0
        if (lane < cA) sidxA = csr[baseA + lane];
        if (lane < cB) sidxB = csr[baseB + lane];
        if (PASS1) {
            if (lane < cA) { dvA = dinv[sidxA]; sdA += dvA; }
            if (lane < cB) { dvB = dinv[sidxB]; sdB += dvB; }
        }
        int itA = (cA + 3) >> 2, itB = (cB + 3) >> 2;
        int iters = itA > itB ? itA : itB;
#pragma unroll 2
        for (int i = 0; i < iters; ++i) {
            int t = 4 * i + q;   // t <= 63 always
            // shfls outside divergent guards (all source lanes active)
            int sA = __shfl(sidxA, t);
            int sB = __shfl(sidxB, t);
            float dA = 0.f, dB = 0.f;
            if (PASS1) { dA = __shfl(dvA, t); dB = __shfl(dvB, t); }
            if (t < cA) {
                uint4 v = xh4[((size_t)sA << 4) + ql];
                f16x8 h = __builtin_bit_cast(f16x8, v);
#pragma unroll
                for (int j = 0; j < 8; ++j) {
                    if (PASS1) accA[j] = fmaf(dA, (float)h[j], accA[j]);
                    else       accA[j] += (float)h[j];
                }
            }
            if (t < cB) {
                uint4 v = xh4[((size_t)sB << 4) + ql];
                f16x8 h = __builtin_bit_cast(f16x8, v);
#pragma unroll
                for (int j = 0; j < 8; ++j) {
                    if (PASS1) accB[j] = fmaf(dB, (float)h[j], accB[j]);
                    else       accB[j] += (float)h[j];
                }
            }
        }
        baseA += 64;
        baseB += 64;
    }

#pragma unroll
    for (int j = 0; j < 8; ++j) {
        accA[j] += __shfl_xor(accA[j], 16);
        accA[j] += __shfl_xor(accA[j], 32);
        accB[j] += __shfl_xor(accB[j], 16);
        accB[j] += __shfl_xor(accB[j], 32);
    }

    if (PASS1) {
#pragma unroll
        for (int d = 1; d < 64; d <<= 1) {
            sdA += __shfl_xor(sdA, d);
            sdB += __shfl_xor(sdB, d);
        }
        if (lane == 0) {
            svec[gwA] = diA * (diA + sdA);
            if (vB) svec[gwB] = diB * (diB + sdB);
        }
    }
    if (q == 0) {
        // pass 1 stores di^2 * acc (prescaled for pass 2); pass 2 stores di * acc
        float fA = PASS1 ? diA * diA : diA;
        float fB = PASS1 ? diB * diB : diB;
        f16x8 ha, hb;
#pragma unroll
        for (int j = 0; j < 8; ++j) {
            ha[j] = (_Float16)(fA * accA[j]);
            hb[j] = (_Float16)(fB * accB[j]);
        }
        *(uint4*)(qout + (size_t)gwA * 128 + ql * 8) = __builtin_bit_cast(uint4, ha);
        if (vB) *(uint4*)(qout + (size_t)gwB * 128 + ql * 8) = __builtin_bit_cast(uint4, hb);
    }
}

// out = relu( X @ W12 + svec ⊗ cvec + b2 ) — MFMA bf16 split-precision
// (X@W = Xhi·Whi + Xlo·Whi + Xhi·Wlo). A is f16 (one uint4 per fragment);
// the bf16 hi/lo split of an f16 value is EXACT (8+3 mantissa bits).
// 256 threads / 4 waves; block covers 128 rows; wave owns 32 rows x 8
// col-tiles. W fragments in LDS (64KB). Reads ws, writes d_out (no alias).
__launch_bounds__(256)
__global__ void k_gemm_mfma(const ushort* __restrict__ Xh,
                            const ushort* __restrict__ wph, const ushort* __restrict__ wpl,
                            const float* __restrict__ svec, const float* __restrict__ cvec,
                            const float* __restrict__ b2, float* __restrict__ out, int N) {
    __shared__ uint4 wsh[2048];  // 32 KB
    __shared__ uint4 wsl[2048];  // 32 KB
    int tid = threadIdx.x;
    int lane = tid & 63;
    int wv = tid >> 6;
    int row0 = blockIdx.x * 128;

#pragma unroll
    for (int it = 0; it < 8; ++it) {
        wsh[it * 256 + tid] = ((const uint4*)wph)[it * 256 + tid];
        wsl[it * 256 + tid] = ((const uint4*)wpl)[it * 256 + tid];
    }

    bf16x8 ah[2][4], al[2][4];
#pragma unroll
    for (int s = 0; s < 2; ++s) {
#pragma unroll
        for (int kb = 0; kb < 4; ++kb) {
            int row = row0 + wv * 32 + s * 16 + (lane & 15);
            int kbase = kb * 32 + (lane >> 4) * 8;
            f16x8 hv;
            if (row < N) {
                uint4 raw = *(const uint4*)(Xh + (size_t)row * 128 + kbase);
                hv = __builtin_bit_cast(f16x8, raw);
            } else {
#pragma unroll
                for (int i = 0; i < 8; ++i) hv[i] = (_Float16)0.f;
            }
            bf16x8 hh, ll;
#pragma unroll
            for (int i = 0; i < 8; ++i) {
                float f = (float)hv[i];
                ushort h = bf16rn(f);
                hh[i] = (short)h;
                ll[i] = (short)bf16rn(f - bf16tof(h));
            }
            ah[s][kb] = hh;
            al[s][kb] = ll;
        }
    }
    __syncthreads();

    f32x4 acc[2][8];
#pragma unroll
    for (int s = 0; s < 2; ++s)
#pragma unroll
        for (int nt = 0; nt < 8; ++nt) acc[s][nt] = (f32x4)(0.f);

#pragma unroll
    for (int nt = 0; nt < 8; ++nt) {
#pragma unroll
        for (int kb = 0; kb < 4; ++kb) {
            uint4 rh = wsh[(nt * 4 + kb) * 64 + lane];
            uint4 rl = wsl[(nt * 4 + kb) * 64 + lane];
            bf16x8 bh = __builtin_bit_cast(bf16x8, rh);
            bf16x8 bl = __builtin_bit_cast(bf16x8, rl);
            acc[0][nt] = __builtin_amdgcn_mfma_f32_16x16x32_bf16(ah[0][kb], bh, acc[0][nt], 0, 0, 0);
            acc[0][nt] = __builtin_amdgcn_mfma_f32_16x16x32_bf16(al[0][kb], bh, acc[0][nt], 0, 0, 0);
            acc[0][nt] = __builtin_amdgcn_mfma_f32_16x16x32_bf16(ah[0][kb], bl, acc[0][nt], 0, 0, 0);
            acc[1][nt] = __builtin_amdgcn_mfma_f32_16x16x32_bf16(ah[1][kb], bh, acc[1][nt], 0, 0, 0);
            acc[1][nt] = __builtin_amdgcn_mfma_f32_16x16x32_bf16(al[1][kb], bh, acc[1][nt], 0, 0, 0);
            acc[1][nt] = __builtin_amdgcn_mfma_f32_16x16x32_bf16(ah[1][kb], bl, acc[1][nt], 0, 0, 0);
        }
    }

    float cv[8], bv[8];
#pragma unroll
    for (int nt = 0; nt < 8; ++nt) {
        cv[nt] = cvec[nt * 16 + (lane & 15)];
        bv[nt] = b2[nt * 16 + (lane & 15)];
    }
#pragma unroll
    for (int s = 0; s < 2; ++s) {
#pragma unroll
        for (int r = 0; r < 4; ++r) {
            int row = row0 + wv * 32 + s * 16 + (lane >> 4) * 4 + r;
            if (row < N) {
                float sv = svec[row];
#pragma unroll
                for (int nt = 0; nt < 8; ++nt) {
                    float o = fmaxf(acc[s][nt][r] + sv * cv[nt] + bv[nt], 0.f);
                    out[(size_t)row * 128 + nt * 16 + (lane & 15)] = o;
                }
            }
        }
    }
}

extern "C" void kernel_launch(void* const* d_in, const int* in_sizes, int n_in,
                              void* d_out, int out_size, void* d_ws, size_t ws_size,
                              hipStream_t stream) {
    const float* x  = (const float*)d_in[0];
    const int*   ei = (const int*)d_in[1];
    const float* W1 = (const float*)d_in[2];
    const float* b1 = (const float*)d_in[3];
    const float* W2 = (const float*)d_in[4];
    const float* b2 = (const float*)d_in[5];
    float* out = (float*)d_out;

    int N = in_sizes[0] / 128;
    int E = in_sizes[1] / 2;
    const int* srcE = ei;
    const int* dstE = ei + E;

    int nbins = (N + 511) >> BINSH;            // 196 for N=100000 (<=256)
    int nblocksB = (E + EPB - 1) / EPB;        // 391 for E=1.6M
    int L = nbins * nblocksB;                  // 76636
    int nbL = (L + 255) / 256;                 // 300 <= 512

    char* w = (char*)d_ws;
    size_t off = 0;
    auto alloc = [&](size_t bytes) {
        void* p = w + off;
        off = WS_ALIGN(off + bytes);
        return p;
    };
    ushort* xh    = (ushort*)alloc((size_t)N * 256);   // also t2h (xh dead in pass 2)
    ushort* t1h   = (ushort*)alloc((size_t)N * 256);   // part aliases here early
    int*   csr    = (int*)alloc((size_t)E * 4);
    int*   hist   = (int*)alloc((size_t)L * 4);
    int*   hists  = (int*)alloc((size_t)L * 4);
    int*   bsums  = (int*)alloc(4096);
    int*   offs   = (int*)alloc((size_t)(N + 1) * 4);
    float* dinv   = (float*)alloc((size_t)N * 4);
    float* svec   = (float*)alloc((size_t)N * 4);
    float* w12    = (float*)alloc(128 * 128 * 4);
    ushort* wph   = (ushort*)alloc(128 * 128 * 2);
    ushort* wpl   = (ushort*)alloc(128 * 128 * 2);
    float* cvec   = (float*)alloc(128 * 4);
    (void)ws_size; (void)n_in; (void)out_size;

    uint* part = (uint*)t1h;    // E*4 <= N*256; dead before t1h is written
    ushort* t2h = xh;           // xh dead once pass 1 has consumed it

    int cb = 512;  // conversion rider blocks
    // 1: hist + conv(f16) + w12 + cvec
    k_hist_fused<<<nblocksB + cb + 65, 256, 0, stream>>>(srcE, dstE, hist, E, N, nbins,
                                                         nblocksB, x, xh, W1, b1, W2,
                                                         w12, cvec, cb);
    // 2-3: scan histogram (block-local + block-sum scan; consumers add inline)
    k_scanA<<<nbL, 256, 0, stream>>>(hist, hists, bsums, L);
    k_scan2<<<1, 512, 0, stream>>>(bsums, nbL);
    // 4: partition + wpack rider
    k_part_fused<<<nblocksB + 8, 256, 0, stream>>>(srcE, dstE, hists, bsums, part,
                                                   E, N, nbins, nblocksB, w12, wph, wpl);
    // 5: per-bin count/scan/fill -> csr, offs, dinv
    k_bin<<<nbins, 256, 0, stream>>>(part, hists, bsums, hist, nbins, nblocksB, N,
                                     csr, offs, dinv);
    // 6: pass 1: t1h = f16(di^2*(di*x_self + sum dj*x_j)) + svec (part dead)
    k_aggq<1><<<(N + 7) / 8, 256, 0, stream>>>(xh, dinv, t1h, svec, offs, csr, N);
    // 7: pass 2: t2h = f16(di * sum(t1h))  (xh dead -> t2h reuses it)
    k_aggq<0><<<(N + 7) / 8, 256, 0, stream>>>(t1h, dinv, t2h, nullptr, offs, csr, N);
    // 8: out = relu(t2h @ W12 + svec ⊗ cvec + b2), MFMA
    k_gemm_mfma<<<(N + 127) / 128, 256, 0, stream>>>(t2h, wph, wpl, svec, cvec, b2, out, N);
}